// Round 4
// baseline (2060.380 us; speedup 1.0000x reference)
//
#include <hip/hip_runtime.h>
#include <math.h>

#define B_   128
#define L_   197
#define C_   768
#define Nv_  196
#define Lt_  32
#define Ct_  512
#define H_   12
#define DH_  64
#define DPP_ 256
#define MTOK 25088   // B_*Nv_

// ---------------------------------------------------------------------------
// Generic fp32 NT GEMM: C[m][n] = scale * sum_k A[m][k]*B[n][k] (+ bias[n])
// Reg-staged double-buffered LDS, ONE barrier per k-tile.
// Thread (tx,ty) owns rows m0+ty*8..+7, cols {n0+tx*4..+3, n0+64+tx*4..+3}
//  -> Bs reads are stride-4-dword (2-way bank = free); As reads broadcast.
// GATHER_A: A row m -> vis_tok row: x[((n+1)*B + b)*C + k], m = b*196+n
// BOUNDS:   guard M/N edges (gram 196x196)
// EPI==1:   MLP epilogue: gelu(h)=h*sigmoid(1.702h), partial dots with W2
//           -> partials[m][6][2] (deterministic, no atomics)
// ---------------------------------------------------------------------------
template<int GATHER_A, int BOUNDS, int EPI>
__global__ __launch_bounds__(256)
void gemm_nt(const float* __restrict__ A, const float* __restrict__ Bm,
             const float* __restrict__ bias, float* __restrict__ C,
             int M, int N, int K, float scale,
             long strideA, long strideC,
             const float* __restrict__ W2, float* __restrict__ partials)
{
    __shared__ float As[2][16][132];
    __shared__ float Bs[2][16][132];
    const int tid = threadIdx.x;
    const int tx = tid & 15, ty = tid >> 4;
    const int m0 = blockIdx.x * 128, n0 = blockIdx.y * 128;
    const int bz = blockIdx.z;
    const float* Ab = A  + (size_t)bz * strideA;
    const float* Bb = Bm + (size_t)bz * strideA;
    float* Cb = C + (size_t)bz * strideC;

    const int lrow = tid >> 2;        // 0..63 (this thread stages rows lrow, lrow+64)
    const int lk   = (tid & 3) << 2;  // 0,4,8,12

    const float* aptr[2]; const float* bptr[2];
    bool aval[2], bval[2];
#pragma unroll
    for (int Lq = 0; Lq < 2; ++Lq) {
        int row = lrow + Lq * 64;
        int gr = m0 + row;
        aval[Lq] = (!BOUNDS) || (gr < M);
        if (GATHER_A) {
            int bb = gr / Nv_, n = gr - bb * Nv_;
            aptr[Lq] = A + ((size_t)(n + 1) * B_ + bb) * C_ + lk;
        } else {
            aptr[Lq] = Ab + (size_t)(aval[Lq] ? gr : 0) * K + lk;
        }
        int gc = n0 + row;
        bval[Lq] = (!BOUNDS) || (gc < N);
        bptr[Lq] = Bb + (size_t)(bval[Lq] ? gc : 0) * K + lk;
    }

    float4 ra[2], rb[2];
    float acc[8][8];
#pragma unroll
    for (int r = 0; r < 8; ++r)
#pragma unroll
        for (int c = 0; c < 8; ++c) acc[r][c] = 0.f;

    // prologue: tile 0 -> LDS buf 0
#pragma unroll
    for (int Lq = 0; Lq < 2; ++Lq) {
        ra[Lq] = aval[Lq] ? *(const float4*)(aptr[Lq]) : make_float4(0.f,0.f,0.f,0.f);
        rb[Lq] = bval[Lq] ? *(const float4*)(bptr[Lq]) : make_float4(0.f,0.f,0.f,0.f);
    }
#pragma unroll
    for (int Lq = 0; Lq < 2; ++Lq) {
        int row = lrow + Lq * 64;
        As[0][lk+0][row] = ra[Lq].x; As[0][lk+1][row] = ra[Lq].y;
        As[0][lk+2][row] = ra[Lq].z; As[0][lk+3][row] = ra[Lq].w;
        Bs[0][lk+0][row] = rb[Lq].x; Bs[0][lk+1][row] = rb[Lq].y;
        Bs[0][lk+2][row] = rb[Lq].z; Bs[0][lk+3][row] = rb[Lq].w;
    }
    __syncthreads();

    const int nk = K >> 4;
    int cur = 0;
    for (int t = 1; t <= nk; ++t) {
        if (t < nk) {   // issue next tile's loads BEFORE compute (latency hides)
#pragma unroll
            for (int Lq = 0; Lq < 2; ++Lq) {
                ra[Lq] = aval[Lq] ? *(const float4*)(aptr[Lq] + t * 16) : make_float4(0.f,0.f,0.f,0.f);
                rb[Lq] = bval[Lq] ? *(const float4*)(bptr[Lq] + t * 16) : make_float4(0.f,0.f,0.f,0.f);
            }
        }
#pragma unroll
        for (int kk = 0; kk < 16; ++kk) {
            float a[8], bfr[8];
            *(float4*)&a[0]   = *(const float4*)&As[cur][kk][ty * 8];
            *(float4*)&a[4]   = *(const float4*)&As[cur][kk][ty * 8 + 4];
            *(float4*)&bfr[0] = *(const float4*)&Bs[cur][kk][tx * 4];
            *(float4*)&bfr[4] = *(const float4*)&Bs[cur][kk][64 + tx * 4];
#pragma unroll
            for (int r = 0; r < 8; ++r)
#pragma unroll
                for (int c = 0; c < 8; ++c)
                    acc[r][c] = fmaf(a[r], bfr[c], acc[r][c]);
        }
        if (t < nk) {
            const int nb = cur ^ 1;   // buf nb held tile t-1: fully consumed before last barrier
#pragma unroll
            for (int Lq = 0; Lq < 2; ++Lq) {
                int row = lrow + Lq * 64;
                As[nb][lk+0][row] = ra[Lq].x; As[nb][lk+1][row] = ra[Lq].y;
                As[nb][lk+2][row] = ra[Lq].z; As[nb][lk+3][row] = ra[Lq].w;
                Bs[nb][lk+0][row] = rb[Lq].x; Bs[nb][lk+1][row] = rb[Lq].y;
                Bs[nb][lk+2][row] = rb[Lq].z; Bs[nb][lk+3][row] = rb[Lq].w;
            }
            __syncthreads();
            cur = nb;
        }
    }

    if constexpr (EPI == 0) {
#pragma unroll
        for (int r = 0; r < 8; ++r) {
            int gr = m0 + ty * 8 + r;
            if (BOUNDS && gr >= M) continue;
#pragma unroll
            for (int half = 0; half < 2; ++half) {
                int gc = n0 + half * 64 + tx * 4;
                if (!BOUNDS) {
                    float4 v;
                    v.x = acc[r][half*4+0] * scale;
                    v.y = acc[r][half*4+1] * scale;
                    v.z = acc[r][half*4+2] * scale;
                    v.w = acc[r][half*4+3] * scale;
                    if (bias) {
                        v.x += bias[gc]; v.y += bias[gc+1];
                        v.z += bias[gc+2]; v.w += bias[gc+3];
                    }
                    *(float4*)(Cb + (size_t)gr * N + gc) = v;
                } else {
#pragma unroll
                    for (int c = 0; c < 4; ++c) {
                        if (gc + c < N) {
                            float v = acc[r][half*4+c] * scale;
                            if (bias) v += bias[gc+c];
                            Cb[(size_t)gr * N + gc + c] = v;
                        }
                    }
                }
            }
        }
    } else {
        // MLP epilogue: gelu then per-thread partial dot with W2 rows
        float p0[8], p1[8];
#pragma unroll
        for (int r = 0; r < 8; ++r) { p0[r] = 0.f; p1[r] = 0.f; }
#pragma unroll
        for (int c = 0; c < 8; ++c) {
            int gc = n0 + (c >> 2) * 64 + tx * 4 + (c & 3);
            float w20 = W2[gc], w21 = W2[C_ + gc];
            float b1v = bias[gc];
#pragma unroll
            for (int r = 0; r < 8; ++r) {
                float h  = acc[r][c] + b1v;
                float gl = h / (1.f + expf(-1.702f * h));
                p0[r] = fmaf(gl, w20, p0[r]);
                p1[r] = fmaf(gl, w21, p1[r]);
            }
        }
#pragma unroll
        for (int off = 8; off; off >>= 1) {
#pragma unroll
            for (int r = 0; r < 8; ++r) {
                p0[r] += __shfl_xor(p0[r], off, 16);
                p1[r] += __shfl_xor(p1[r], off, 16);
            }
        }
        if (tx == 0) {
#pragma unroll
            for (int r = 0; r < 8; ++r) {
                int gr = m0 + ty * 8 + r;
                partials[(size_t)gr * 12 + blockIdx.y * 2 + 0] = p0[r];
                partials[(size_t)gr * 12 + blockIdx.y * 2 + 1] = p1[r];
            }
        }
    }
}

// ---------------------------------------------------------------------------
// Attention per (b,h): scores=qK^T/8, softmax over 32, ctx=attn@V,
// fused = ctx + vis_tok written IN-PLACE over q.
// Wave-independent: q/attn broadcasts via __shfl; zero barriers in the loop.
// Lanes >=32 compute a duplicated half (identical values), so width-32
// butterflies match the original bit-for-bit.
// ---------------------------------------------------------------------------
__global__ __launch_bounds__(256)
void attn_kernel(const float* __restrict__ q, const float* __restrict__ k,
                 const float* __restrict__ v, const float* __restrict__ x,
                 float* __restrict__ fused)
{
    __shared__ float Ks[Lt_][DH_ + 1];
    __shared__ float Vs[Lt_][DH_ + 1];
    const int bh = blockIdx.x;
    const int b = bh / H_, h = bh - b * H_;
    const int tid = threadIdx.x;
    const int wv = tid >> 6, lane = tid & 63;

    for (int idx = tid; idx < Lt_ * 16; idx += 256) {  // 512 float4
        int l = idx >> 4, dq = (idx & 15) << 2;
        size_t off = ((size_t)(b * Lt_ + l)) * C_ + h * DH_ + dq;
        float4 kv4 = *(const float4*)(k + off);
        Ks[l][dq] = kv4.x; Ks[l][dq + 1] = kv4.y; Ks[l][dq + 2] = kv4.z; Ks[l][dq + 3] = kv4.w;
        float4 vv4 = *(const float4*)(v + off);
        Vs[l][dq] = vv4.x; Vs[l][dq + 1] = vv4.y; Vs[l][dq + 2] = vv4.z; Vs[l][dq + 3] = vv4.w;
    }
    __syncthreads();

    const int lkey = lane & 31;
    for (int it = 0; it < 49; ++it) {
        int n = it * 4 + wv;   // always < 196
        size_t qoff = ((size_t)(b * Nv_ + n)) * C_ + h * DH_ + lane;
        float qv = q[qoff];
        float s = 0.f;
#pragma unroll
        for (int d = 0; d < DH_; ++d)
            s = fmaf(__shfl(qv, d, 64), Ks[lkey][d], s);
        s *= 0.125f;
        float mx = s;
#pragma unroll
        for (int off = 16; off; off >>= 1) mx = fmaxf(mx, __shfl_xor(mx, off, 32));
        float p = expf(s - mx);
        float sum = p;
#pragma unroll
        for (int off = 16; off; off >>= 1) sum += __shfl_xor(sum, off, 32);
        float av = p / sum;
        float c = 0.f;
#pragma unroll
        for (int l = 0; l < Lt_; ++l)
            c = fmaf(__shfl(av, l, 64), Vs[l][lane], c);
        float xv = x[((size_t)(n + 1) * B_ + b) * C_ + h * DH_ + lane];
        fused[qoff] = c + xv;
    }
}

// ---------------------------------------------------------------------------
// keep decisions: logits from partials (+b2), gumbel, policy bits, keep_prob
// ---------------------------------------------------------------------------
__global__ __launch_bounds__(256)
void keep_kernel(const float* __restrict__ partials, const float* __restrict__ b2,
                 const float* __restrict__ gumbel, float* __restrict__ policy,
                 float* __restrict__ keep_prob)
{
    int m = blockIdx.x * 256 + threadIdx.x;   // < 25088 exactly
    int b = m / Nv_, n = m - b * Nv_;
    float l0 = b2[0], l1 = b2[1];
#pragma unroll
    for (int t = 0; t < 6; ++t) {
        l0 += partials[(size_t)m * 12 + t * 2 + 0];
        l1 += partials[(size_t)m * 12 + t * 2 + 1];
    }
    const float UHI = (float)(1.0 - 1e-6);
    float U0 = fminf(fmaxf(gumbel[(size_t)m * 2 + 0], 1e-6f), UHI);
    float U1 = fminf(fmaxf(gumbel[(size_t)m * 2 + 1], 1e-6f), UHI);
    float t0 = (float)log((double)U0);
    float g0 = -(float)log((double)(-t0));
    float t1 = (float)log((double)U1);
    float g1 = -(float)log((double)(-t1));
    float dlog = (l1 + g1) - (l0 + g0);
    float kp = 1.f / (1.f + expf(-dlog));
    policy[(size_t)b * 197 + 1 + n] = (dlog > 0.f) ? 1.f : 0.f;
    if (n == 0) policy[(size_t)b * 197] = 1.f;
    keep_prob[m] = kp;
}

// deterministic per-batch keep_prob sum
__global__ __launch_bounds__(256)
void batch_reduce(const float* __restrict__ keep_prob, float* __restrict__ sum_kp)
{
    __shared__ float part[4];
    int b = blockIdx.x, tid = threadIdx.x;
    float vs = (tid < Nv_) ? keep_prob[(size_t)b * Nv_ + tid] : 0.f;
#pragma unroll
    for (int off = 32; off; off >>= 1) vs += __shfl_xor(vs, off, 64);
    if ((tid & 63) == 0) part[tid >> 6] = vs;
    __syncthreads();
    if (tid == 0) sum_kp[b] = part[0] + part[1] + part[2] + part[3];
}

// phi row-normalize * sqrt(max(kp/(mean kp+eps),1e-6)), in place (rel==1)
__global__ __launch_bounds__(256)
void pw_scale(float* __restrict__ phi, const float* __restrict__ keep_prob,
              const float* __restrict__ sum_kp)
{
    int m = blockIdx.x * 4 + (threadIdx.x >> 6);
    int lane = threadIdx.x & 63;
    float4* row = (float4*)phi + (size_t)m * 64;
    float4 vv = row[lane];
    float ss = vv.x * vv.x + vv.y * vv.y + vv.z * vv.z + vv.w * vv.w;
#pragma unroll
    for (int off = 32; off; off >>= 1) ss += __shfl_xor(ss, off, 64);
    float nrm = fmaxf(sqrtf(ss), 1e-12f);
    int b = m / Nv_;
    float kp = keep_prob[m];
    float meanw = sum_kp[b] * (1.f / 196.f);
    float wn = fmaxf(kp / (meanw + 1e-12f), 1e-6f);
    float sc = sqrtf(wn) / nrm;
    vv.x *= sc; vv.y *= sc; vv.z *= sc; vv.w *= sc;
    row[lane] = vv;
}

// ---------------------------------------------------------------------------
// Per-batch blocked Cholesky logdet. Row stride 197 (five mod 32, coprime ->
// column walks cycle all banks). Panel width 14.
// ---------------------------------------------------------------------------
#define LS_   197
#define PBS_  14

__global__ __launch_bounds__(256)
void chol_kernel(const float* __restrict__ G, float* __restrict__ logdet_arr)
{
    extern __shared__ float sm[];
    float* Am  = sm;                 // 196 * 197
    float* col = sm + 196 * LS_;     // 196
    const int b = blockIdx.x, tid = threadIdx.x;
    const float* Gb = G + (size_t)b * Nv_ * Nv_;

    for (int idx = tid; idx < Nv_ * 49; idx += 256) {
        int i = idx / 49, c4 = (idx - i * 49) * 4;
        float4 v = *(const float4*)(Gb + (size_t)i * Nv_ + c4);
        if (i >= c4 && i < c4 + 4) (&v.x)[i - c4] += 1.00001f;
        float* dst = Am + i * LS_ + c4;
        dst[0] = v.x; dst[1] = v.y; dst[2] = v.z; dst[3] = v.w;
    }
    __syncthreads();

    float acc = 0.f;
    const int tx = tid & 15, ty = tid >> 4;

    for (int p = 0; p < Nv_ / PBS_; ++p) {
        const int j0 = p * PBS_;
        for (int jj = j0; jj < j0 + PBS_; ++jj) {
            float piv = Am[jj * LS_ + jj];
            if (tid == 0) acc += logf(piv);
            float inv = 1.f / sqrtf(piv);
            for (int i = jj + 1 + tid; i < Nv_; i += 256) {
                float v = Am[i * LS_ + jj] * inv;
                Am[i * LS_ + jj] = v;
                col[i] = v;
            }
            __syncthreads();
            for (int k = jj + 1; k < j0 + PBS_; ++k) {
                float ck = col[k];
                for (int i = k + tid; i < Nv_; i += 256)
                    Am[i * LS_ + k] = fmaf(-col[i], ck, Am[i * LS_ + k]);
            }
            __syncthreads();
        }
        const int j1 = j0 + PBS_;
        if (j1 >= Nv_) break;
        const int s = Nv_ - j1;
        const int nb = (s + 63) >> 6;
        for (int rb = 0; rb < nb; ++rb)
            for (int cb = 0; cb <= rb; ++cb) {
                const int i0 = j1 + rb * 64;
                const int k0 = j1 + cb * 64;
                float accs[4][4];
#pragma unroll
                for (int r = 0; r < 4; ++r)
#pragma unroll
                    for (int c = 0; c < 4; ++c) accs[r][c] = 0.f;
                float Li[4][PBS_];
#pragma unroll
                for (int r = 0; r < 4; ++r) {
                    int i = i0 + ty + 16 * r; if (i > 195) i = 195;
#pragma unroll
                    for (int t = 0; t < PBS_; ++t) Li[r][t] = Am[i * LS_ + j0 + t];
                }
#pragma unroll
                for (int t = 0; t < PBS_; ++t) {
                    float Lk[4];
#pragma unroll
                    for (int c = 0; c < 4; ++c) {
                        int kx = k0 + 4 * tx + c; if (kx > 195) kx = 195;
                        Lk[c] = Am[kx * LS_ + j0 + t];
                    }
#pragma unroll
                    for (int r = 0; r < 4; ++r)
#pragma unroll
                        for (int c = 0; c < 4; ++c)
                            accs[r][c] = fmaf(Li[r][t], Lk[c], accs[r][c]);
                }
#pragma unroll
                for (int r = 0; r < 4; ++r) {
                    int i = i0 + ty + 16 * r;
                    if (i < Nv_) {
#pragma unroll
                        for (int c = 0; c < 4; ++c) {
                            int kx = k0 + 4 * tx + c;
                            if (kx < Nv_) Am[i * LS_ + kx] -= accs[r][c];
                        }
                    }
                }
            }
        __syncthreads();
    }
    if (tid == 0) logdet_arr[b] = acc;
}

// deterministic serial finalize
__global__ void finalize_kernel(const float* __restrict__ sum_kp,
                                const float* __restrict__ logdet_arr,
                                float* __restrict__ out)
{
    float tot = 0.f, ld = 0.f;
    for (int b = 0; b < B_; ++b) { tot += sum_kp[b]; ld += logdet_arr[b]; }
    float mean = tot * (1.f / 25088.f);
    float d = mean - 0.7f;
    out[25216] = d * d;
    out[25217] = -ld * (1.f / 128.f);
}

// ---------------------------------------------------------------------------
extern "C" void kernel_launch(void* const* d_in, const int* in_sizes, int n_in,
                              void* d_out, int out_size, void* d_ws, size_t ws_size,
                              hipStream_t stream)
{
    const float* x      = (const float*)d_in[0];
    const float* text   = (const float*)d_in[1];
    const float* gumbel = (const float*)d_in[2];
    const float* Wq     = (const float*)d_in[3];
    const float* bq     = (const float*)d_in[4];
    const float* Wk     = (const float*)d_in[5];
    const float* bk     = (const float*)d_in[6];
    const float* Wv     = (const float*)d_in[7];
    const float* bv     = (const float*)d_in[8];
    const float* W1     = (const float*)d_in[9];
    const float* b1     = (const float*)d_in[10];
    const float* W2     = (const float*)d_in[11];
    const float* b2     = (const float*)d_in[12];
    const float* Wdpp   = (const float*)d_in[13];
    float* out = (float*)d_out;

    float* ws = (float*)d_ws;
    float* q          = ws;                       // 25088*768
    float* kbuf       = q + 19267584;
    float* vbuf       = kbuf + 3145728;
    float* phi        = vbuf + 3145728;
    float* partials   = phi + 6422528;
    float* keep_prob  = partials + 301056;
    float* sum_kp     = keep_prob + 25088;
    float* logdet_arr = sum_kp + 128;
    float* G          = ws;                       // reuse q region (dead after MLP)

    dim3 blk(256);

    gemm_nt<0,0,0><<<dim3(32,6,1), blk, 0, stream>>>(text, Wk, bk, kbuf, 4096, 768, 512, 1.f, 0, 0, nullptr, nullptr);
    gemm_nt<0,0,0><<<dim3(32,6,1), blk, 0, stream>>>(text, Wv, bv, vbuf, 4096, 768, 512, 1.f, 0, 0, nullptr, nullptr);
    gemm_nt<1,0,0><<<dim3(196,6,1), blk, 0, stream>>>(x, Wq, bq, q, MTOK, 768, 768, 1.f, 0, 0, nullptr, nullptr);
    attn_kernel<<<dim3(B_*H_), blk, 0, stream>>>(q, kbuf, vbuf, x, q);
    gemm_nt<0,0,1><<<dim3(196,6,1), blk, 0, stream>>>(q, W1, b1, nullptr, MTOK, 768, 768, 1.f, 0, 0, W2, partials);
    keep_kernel<<<dim3(98), blk, 0, stream>>>(partials, b2, gumbel, out, keep_prob);
    batch_reduce<<<dim3(B_), blk, 0, stream>>>(keep_prob, sum_kp);
    gemm_nt<1,0,0><<<dim3(196,2,1), blk, 0, stream>>>(x, Wdpp, nullptr, phi, MTOK, 256, 768, 1.f, 0, 0, nullptr, nullptr);
    pw_scale<<<dim3(6272), blk, 0, stream>>>(phi, keep_prob, sum_kp);
    gemm_nt<0,1,0><<<dim3(2,2,B_), blk, 0, stream>>>(phi, phi, nullptr, G, Nv_, Nv_, 256,
                                                     1.0f/(256.0f*196.0f*0.01f),
                                                     (long)Nv_*256, (long)Nv_*Nv_, nullptr, nullptr);
    size_t shb = (size_t)(Nv_ * LS_ + Nv_) * sizeof(float);
    (void)hipFuncSetAttribute((const void*)chol_kernel,
                              hipFuncAttributeMaxDynamicSharedMemorySize, (int)shb);
    chol_kernel<<<dim3(B_), blk, shb, stream>>>(G, logdet_arr);
    finalize_kernel<<<dim3(1), dim3(1), 0, stream>>>(sum_kp, logdet_arr, out);
}

// Round 5
// 1632.809 us; speedup vs baseline: 1.2619x; 1.2619x over previous
//
#include <hip/hip_runtime.h>
#include <math.h>

#define B_   128
#define L_   197
#define C_   768
#define Nv_  196
#define Lt_  32
#define Ct_  512
#define H_   12
#define DH_  64
#define DPP_ 256
#define MTOK 25088   // B_*Nv_

// ---------------------------------------------------------------------------
// Generic fp32 NT GEMM: C[m][n] = scale * sum_k A[m][k]*B[n][k] (+ bias[n])
// Single-buffered LDS (16.9 KB), 2 barriers/k-tile, low VGPR (occupancy!).
// Thread (tx,ty) owns rows m0+ty*8..+7, cols {n0+tx*4..+3, n0+64+tx*4..+3}
//  -> Bs reads are stride-4-dword (2-way bank = free); As reads broadcast.
//  (r4 A/B: conflict fix verified good [3.6e7->7.2e6]; dbuf verified bad
//   [VGPR 184, occ 10.8%] -> reverted to r3 pipeline.)
// GATHER_A: A row m -> vis_tok row: x[((n+1)*B + b)*C + k], m = b*196+n
// BOUNDS:   guard M/N edges (gram 196x196)
// EPI==1:   MLP epilogue: gelu(h)=h*sigmoid(1.702h), partial dots with W2
//           -> partials[m][6][2] (deterministic, no atomics)
// ---------------------------------------------------------------------------
template<int GATHER_A, int BOUNDS, int EPI>
__global__ __launch_bounds__(256)
void gemm_nt(const float* __restrict__ A, const float* __restrict__ Bm,
             const float* __restrict__ bias, float* __restrict__ C,
             int M, int N, int K, float scale,
             long strideA, long strideC,
             const float* __restrict__ W2, float* __restrict__ partials)
{
    __shared__ float As[16][132];
    __shared__ float Bs[16][132];
    const int tid = threadIdx.x;
    const int tx = tid & 15, ty = tid >> 4;
    const int m0 = blockIdx.x * 128, n0 = blockIdx.y * 128;
    const int bz = blockIdx.z;
    const float* Ab = A  + (size_t)bz * strideA;
    const float* Bb = Bm + (size_t)bz * strideA;
    float* Cb = C + (size_t)bz * strideC;

    const int lrow = tid >> 2;        // 0..63 (this thread stages rows lrow, lrow+64)
    const int lk   = (tid & 3) << 2;  // 0,4,8,12

    // precompute per-thread staging pointers (consumed immediately -> no
    // long live ranges, VGPR stays low)
    const float* aptr[2]; const float* bptr[2];
    bool aval[2], bval[2];
#pragma unroll
    for (int Lq = 0; Lq < 2; ++Lq) {
        int row = lrow + Lq * 64;
        int gr = m0 + row;
        aval[Lq] = (!BOUNDS) || (gr < M);
        if (GATHER_A) {
            int bb = gr / Nv_, n = gr - bb * Nv_;
            aptr[Lq] = A + ((size_t)(n + 1) * B_ + bb) * C_ + lk;
        } else {
            aptr[Lq] = Ab + (size_t)(aval[Lq] ? gr : 0) * K + lk;
        }
        int gc = n0 + row;
        bval[Lq] = (!BOUNDS) || (gc < N);
        bptr[Lq] = Bb + (size_t)(bval[Lq] ? gc : 0) * K + lk;
    }

    float acc[8][8];
#pragma unroll
    for (int r = 0; r < 8; ++r)
#pragma unroll
        for (int c = 0; c < 8; ++c) acc[r][c] = 0.f;

    for (int k0 = 0; k0 < K; k0 += 16) {
#pragma unroll
        for (int Lq = 0; Lq < 2; ++Lq) {
            int row = lrow + Lq * 64;
            float4 va = aval[Lq] ? *(const float4*)(aptr[Lq] + k0)
                                 : make_float4(0.f, 0.f, 0.f, 0.f);
            As[lk+0][row] = va.x; As[lk+1][row] = va.y;
            As[lk+2][row] = va.z; As[lk+3][row] = va.w;
            float4 vb = bval[Lq] ? *(const float4*)(bptr[Lq] + k0)
                                 : make_float4(0.f, 0.f, 0.f, 0.f);
            Bs[lk+0][row] = vb.x; Bs[lk+1][row] = vb.y;
            Bs[lk+2][row] = vb.z; Bs[lk+3][row] = vb.w;
        }
        __syncthreads();
#pragma unroll
        for (int kk = 0; kk < 16; ++kk) {
            float a[8], bfr[8];
            *(float4*)&a[0]   = *(const float4*)&As[kk][ty * 8];
            *(float4*)&a[4]   = *(const float4*)&As[kk][ty * 8 + 4];
            *(float4*)&bfr[0] = *(const float4*)&Bs[kk][tx * 4];
            *(float4*)&bfr[4] = *(const float4*)&Bs[kk][64 + tx * 4];
#pragma unroll
            for (int r = 0; r < 8; ++r)
#pragma unroll
                for (int c = 0; c < 8; ++c)
                    acc[r][c] = fmaf(a[r], bfr[c], acc[r][c]);
        }
        __syncthreads();
    }

    if constexpr (EPI == 0) {
#pragma unroll
        for (int r = 0; r < 8; ++r) {
            int gr = m0 + ty * 8 + r;
            if (BOUNDS && gr >= M) continue;
#pragma unroll
            for (int half = 0; half < 2; ++half) {
                int gc = n0 + half * 64 + tx * 4;
                if (!BOUNDS) {
                    float4 v;
                    v.x = acc[r][half*4+0] * scale;
                    v.y = acc[r][half*4+1] * scale;
                    v.z = acc[r][half*4+2] * scale;
                    v.w = acc[r][half*4+3] * scale;
                    if (bias) {
                        v.x += bias[gc]; v.y += bias[gc+1];
                        v.z += bias[gc+2]; v.w += bias[gc+3];
                    }
                    *(float4*)(Cb + (size_t)gr * N + gc) = v;
                } else {
#pragma unroll
                    for (int c = 0; c < 4; ++c) {
                        if (gc + c < N) {
                            float v = acc[r][half*4+c] * scale;
                            if (bias) v += bias[gc+c];
                            Cb[(size_t)gr * N + gc + c] = v;
                        }
                    }
                }
            }
        }
    } else {
        // MLP epilogue: gelu then per-thread partial dot with W2 rows
        float p0[8], p1[8];
#pragma unroll
        for (int r = 0; r < 8; ++r) { p0[r] = 0.f; p1[r] = 0.f; }
#pragma unroll
        for (int c = 0; c < 8; ++c) {
            int gc = n0 + (c >> 2) * 64 + tx * 4 + (c & 3);
            float w20 = W2[gc], w21 = W2[C_ + gc];
            float b1v = bias[gc];
#pragma unroll
            for (int r = 0; r < 8; ++r) {
                float h  = acc[r][c] + b1v;
                float gl = h / (1.f + expf(-1.702f * h));
                p0[r] = fmaf(gl, w20, p0[r]);
                p1[r] = fmaf(gl, w21, p1[r]);
            }
        }
#pragma unroll
        for (int off = 8; off; off >>= 1) {
#pragma unroll
            for (int r = 0; r < 8; ++r) {
                p0[r] += __shfl_xor(p0[r], off, 16);
                p1[r] += __shfl_xor(p1[r], off, 16);
            }
        }
        if (tx == 0) {
#pragma unroll
            for (int r = 0; r < 8; ++r) {
                int gr = m0 + ty * 8 + r;
                partials[(size_t)gr * 12 + blockIdx.y * 2 + 0] = p0[r];
                partials[(size_t)gr * 12 + blockIdx.y * 2 + 1] = p1[r];
            }
        }
    }
}

// ---------------------------------------------------------------------------
// Attention per (b,h): scores=qK^T/8, softmax over 32, ctx=attn@V,
// fused = ctx + vis_tok written IN-PLACE over q.
// Wave-independent: q/attn broadcasts via __shfl; zero barriers in the loop.
// ---------------------------------------------------------------------------
__global__ __launch_bounds__(256)
void attn_kernel(const float* __restrict__ q, const float* __restrict__ k,
                 const float* __restrict__ v, const float* __restrict__ x,
                 float* __restrict__ fused)
{
    __shared__ float Ks[Lt_][DH_ + 1];
    __shared__ float Vs[Lt_][DH_ + 1];
    const int bh = blockIdx.x;
    const int b = bh / H_, h = bh - b * H_;
    const int tid = threadIdx.x;
    const int wv = tid >> 6, lane = tid & 63;

    for (int idx = tid; idx < Lt_ * 16; idx += 256) {  // 512 float4
        int l = idx >> 4, dq = (idx & 15) << 2;
        size_t off = ((size_t)(b * Lt_ + l)) * C_ + h * DH_ + dq;
        float4 kv4 = *(const float4*)(k + off);
        Ks[l][dq] = kv4.x; Ks[l][dq + 1] = kv4.y; Ks[l][dq + 2] = kv4.z; Ks[l][dq + 3] = kv4.w;
        float4 vv4 = *(const float4*)(v + off);
        Vs[l][dq] = vv4.x; Vs[l][dq + 1] = vv4.y; Vs[l][dq + 2] = vv4.z; Vs[l][dq + 3] = vv4.w;
    }
    __syncthreads();

    const int lkey = lane & 31;
    for (int it = 0; it < 49; ++it) {
        int n = it * 4 + wv;   // always < 196
        size_t qoff = ((size_t)(b * Nv_ + n)) * C_ + h * DH_ + lane;
        float qv = q[qoff];
        float s = 0.f;
#pragma unroll
        for (int d = 0; d < DH_; ++d)
            s = fmaf(__shfl(qv, d, 64), Ks[lkey][d], s);
        s *= 0.125f;
        float mx = s;
#pragma unroll
        for (int off = 16; off; off >>= 1) mx = fmaxf(mx, __shfl_xor(mx, off, 32));
        float p = expf(s - mx);
        float sum = p;
#pragma unroll
        for (int off = 16; off; off >>= 1) sum += __shfl_xor(sum, off, 32);
        float av = p / sum;
        float c = 0.f;
#pragma unroll
        for (int l = 0; l < Lt_; ++l)
            c = fmaf(__shfl(av, l, 64), Vs[l][lane], c);
        float xv = x[((size_t)(n + 1) * B_ + b) * C_ + h * DH_ + lane];
        fused[qoff] = c + xv;
    }
}

// ---------------------------------------------------------------------------
// keep decisions: logits from partials (+b2), gumbel, policy bits, keep_prob
// ---------------------------------------------------------------------------
__global__ __launch_bounds__(256)
void keep_kernel(const float* __restrict__ partials, const float* __restrict__ b2,
                 const float* __restrict__ gumbel, float* __restrict__ policy,
                 float* __restrict__ keep_prob)
{
    int m = blockIdx.x * 256 + threadIdx.x;   // < 25088 exactly
    int b = m / Nv_, n = m - b * Nv_;
    float l0 = b2[0], l1 = b2[1];
#pragma unroll
    for (int t = 0; t < 6; ++t) {
        l0 += partials[(size_t)m * 12 + t * 2 + 0];
        l1 += partials[(size_t)m * 12 + t * 2 + 1];
    }
    const float UHI = (float)(1.0 - 1e-6);
    float U0 = fminf(fmaxf(gumbel[(size_t)m * 2 + 0], 1e-6f), UHI);
    float U1 = fminf(fmaxf(gumbel[(size_t)m * 2 + 1], 1e-6f), UHI);
    float t0 = (float)log((double)U0);
    float g0 = -(float)log((double)(-t0));
    float t1 = (float)log((double)U1);
    float g1 = -(float)log((double)(-t1));
    float dlog = (l1 + g1) - (l0 + g0);
    float kp = 1.f / (1.f + expf(-dlog));
    policy[(size_t)b * 197 + 1 + n] = (dlog > 0.f) ? 1.f : 0.f;
    if (n == 0) policy[(size_t)b * 197] = 1.f;
    keep_prob[m] = kp;
}

// deterministic per-batch keep_prob sum
__global__ __launch_bounds__(256)
void batch_reduce(const float* __restrict__ keep_prob, float* __restrict__ sum_kp)
{
    __shared__ float part[4];
    int b = blockIdx.x, tid = threadIdx.x;
    float vs = (tid < Nv_) ? keep_prob[(size_t)b * Nv_ + tid] : 0.f;
#pragma unroll
    for (int off = 32; off; off >>= 1) vs += __shfl_xor(vs, off, 64);
    if ((tid & 63) == 0) part[tid >> 6] = vs;
    __syncthreads();
    if (tid == 0) sum_kp[b] = part[0] + part[1] + part[2] + part[3];
}

// phi row-normalize * sqrt(max(kp/(mean kp+eps),1e-6)), in place (rel==1)
__global__ __launch_bounds__(256)
void pw_scale(float* __restrict__ phi, const float* __restrict__ keep_prob,
              const float* __restrict__ sum_kp)
{
    int m = blockIdx.x * 4 + (threadIdx.x >> 6);
    int lane = threadIdx.x & 63;
    float4* row = (float4*)phi + (size_t)m * 64;
    float4 vv = row[lane];
    float ss = vv.x * vv.x + vv.y * vv.y + vv.z * vv.z + vv.w * vv.w;
#pragma unroll
    for (int off = 32; off; off >>= 1) ss += __shfl_xor(ss, off, 64);
    float nrm = fmaxf(sqrtf(ss), 1e-12f);
    int b = m / Nv_;
    float kp = keep_prob[m];
    float meanw = sum_kp[b] * (1.f / 196.f);
    float wn = fmaxf(kp / (meanw + 1e-12f), 1e-6f);
    float sc = sqrtf(wn) / nrm;
    vv.x *= sc; vv.y *= sc; vv.z *= sc; vv.w *= sc;
    row[lane] = vv;
}

// ---------------------------------------------------------------------------
// Per-batch blocked Cholesky logdet. Row stride 197 (5 mod 32, coprime ->
// column walks cycle all banks). Panel width 14.
// ---------------------------------------------------------------------------
#define LS_   197
#define PBS_  14

__global__ __launch_bounds__(256)
void chol_kernel(const float* __restrict__ G, float* __restrict__ logdet_arr)
{
    extern __shared__ float sm[];
    float* Am  = sm;                 // 196 * 197
    float* col = sm + 196 * LS_;     // 196
    const int b = blockIdx.x, tid = threadIdx.x;
    const float* Gb = G + (size_t)b * Nv_ * Nv_;

    for (int idx = tid; idx < Nv_ * 49; idx += 256) {
        int i = idx / 49, c4 = (idx - i * 49) * 4;
        float4 v = *(const float4*)(Gb + (size_t)i * Nv_ + c4);
        if (i >= c4 && i < c4 + 4) (&v.x)[i - c4] += 1.00001f;
        float* dst = Am + i * LS_ + c4;
        dst[0] = v.x; dst[1] = v.y; dst[2] = v.z; dst[3] = v.w;
    }
    __syncthreads();

    float acc = 0.f;
    const int tx = tid & 15, ty = tid >> 4;

    for (int p = 0; p < Nv_ / PBS_; ++p) {
        const int j0 = p * PBS_;
        for (int jj = j0; jj < j0 + PBS_; ++jj) {
            float piv = Am[jj * LS_ + jj];
            if (tid == 0) acc += logf(piv);
            float inv = 1.f / sqrtf(piv);
            for (int i = jj + 1 + tid; i < Nv_; i += 256) {
                float v = Am[i * LS_ + jj] * inv;
                Am[i * LS_ + jj] = v;
                col[i] = v;
            }
            __syncthreads();
            for (int k = jj + 1; k < j0 + PBS_; ++k) {
                float ck = col[k];
                for (int i = k + tid; i < Nv_; i += 256)
                    Am[i * LS_ + k] = fmaf(-col[i], ck, Am[i * LS_ + k]);
            }
            __syncthreads();
        }
        const int j1 = j0 + PBS_;
        if (j1 >= Nv_) break;
        const int s = Nv_ - j1;
        const int nb = (s + 63) >> 6;
        for (int rb = 0; rb < nb; ++rb)
            for (int cb = 0; cb <= rb; ++cb) {
                const int i0 = j1 + rb * 64;
                const int k0 = j1 + cb * 64;
                float accs[4][4];
#pragma unroll
                for (int r = 0; r < 4; ++r)
#pragma unroll
                    for (int c = 0; c < 4; ++c) accs[r][c] = 0.f;
                float Li[4][PBS_];
#pragma unroll
                for (int r = 0; r < 4; ++r) {
                    int i = i0 + ty + 16 * r; if (i > 195) i = 195;
#pragma unroll
                    for (int t = 0; t < PBS_; ++t) Li[r][t] = Am[i * LS_ + j0 + t];
                }
#pragma unroll
                for (int t = 0; t < PBS_; ++t) {
                    float Lk[4];
#pragma unroll
                    for (int c = 0; c < 4; ++c) {
                        int kx = k0 + 4 * tx + c; if (kx > 195) kx = 195;
                        Lk[c] = Am[kx * LS_ + j0 + t];
                    }
#pragma unroll
                    for (int r = 0; r < 4; ++r)
#pragma unroll
                        for (int c = 0; c < 4; ++c)
                            accs[r][c] = fmaf(Li[r][t], Lk[c], accs[r][c]);
                }
#pragma unroll
                for (int r = 0; r < 4; ++r) {
                    int i = i0 + ty + 16 * r;
                    if (i < Nv_) {
#pragma unroll
                        for (int c = 0; c < 4; ++c) {
                            int kx = k0 + 4 * tx + c;
                            if (kx < Nv_) Am[i * LS_ + kx] -= accs[r][c];
                        }
                    }
                }
            }
        __syncthreads();
    }
    if (tid == 0) logdet_arr[b] = acc;
}

// deterministic serial finalize
__global__ void finalize_kernel(const float* __restrict__ sum_kp,
                                const float* __restrict__ logdet_arr,
                                float* __restrict__ out)
{
    float tot = 0.f, ld = 0.f;
    for (int b = 0; b < B_; ++b) { tot += sum_kp[b]; ld += logdet_arr[b]; }
    float mean = tot * (1.f / 25088.f);
    float d = mean - 0.7f;
    out[25216] = d * d;
    out[25217] = -ld * (1.f / 128.f);
}

// ---------------------------------------------------------------------------
extern "C" void kernel_launch(void* const* d_in, const int* in_sizes, int n_in,
                              void* d_out, int out_size, void* d_ws, size_t ws_size,
                              hipStream_t stream)
{
    const float* x      = (const float*)d_in[0];
    const float* text   = (const float*)d_in[1];
    const float* gumbel = (const float*)d_in[2];
    const float* Wq     = (const float*)d_in[3];
    const float* bq     = (const float*)d_in[4];
    const float* Wk     = (const float*)d_in[5];
    const float* bk     = (const float*)d_in[6];
    const float* Wv     = (const float*)d_in[7];
    const float* bv     = (const float*)d_in[8];
    const float* W1     = (const float*)d_in[9];
    const float* b1     = (const float*)d_in[10];
    const float* W2     = (const float*)d_in[11];
    const float* b2     = (const float*)d_in[12];
    const float* Wdpp   = (const float*)d_in[13];
    float* out = (float*)d_out;

    float* ws = (float*)d_ws;
    float* q          = ws;                       // 25088*768
    float* kbuf       = q + 19267584;
    float* vbuf       = kbuf + 3145728;
    float* phi        = vbuf + 3145728;
    float* partials   = phi + 6422528;
    float* keep_prob  = partials + 301056;
    float* sum_kp     = keep_prob + 25088;
    float* logdet_arr = sum_kp + 128;
    float* G          = ws;                       // reuse q region (dead after MLP)

    dim3 blk(256);

    gemm_nt<0,0,0><<<dim3(32,6,1), blk, 0, stream>>>(text, Wk, bk, kbuf, 4096, 768, 512, 1.f, 0, 0, nullptr, nullptr);
    gemm_nt<0,0,0><<<dim3(32,6,1), blk, 0, stream>>>(text, Wv, bv, vbuf, 4096, 768, 512, 1.f, 0, 0, nullptr, nullptr);
    gemm_nt<1,0,0><<<dim3(196,6,1), blk, 0, stream>>>(x, Wq, bq, q, MTOK, 768, 768, 1.f, 0, 0, nullptr, nullptr);
    attn_kernel<<<dim3(B_*H_), blk, 0, stream>>>(q, kbuf, vbuf, x, q);
    gemm_nt<0,0,1><<<dim3(196,6,1), blk, 0, stream>>>(q, W1, b1, nullptr, MTOK, 768, 768, 1.f, 0, 0, W2, partials);
    keep_kernel<<<dim3(98), blk, 0, stream>>>(partials, b2, gumbel, out, keep_prob);
    batch_reduce<<<dim3(B_), blk, 0, stream>>>(keep_prob, sum_kp);
    gemm_nt<1,0,0><<<dim3(196,2,1), blk, 0, stream>>>(x, Wdpp, nullptr, phi, MTOK, 256, 768, 1.f, 0, 0, nullptr, nullptr);
    pw_scale<<<dim3(6272), blk, 0, stream>>>(phi, keep_prob, sum_kp);
    gemm_nt<0,1,0><<<dim3(2,2,B_), blk, 0, stream>>>(phi, phi, nullptr, G, Nv_, Nv_, 256,
                                                     1.0f/(256.0f*196.0f*0.01f),
                                                     (long)Nv_*256, (long)Nv_*Nv_, nullptr, nullptr);
    size_t shb = (size_t)(Nv_ * LS_ + Nv_) * sizeof(float);
    (void)hipFuncSetAttribute((const void*)chol_kernel,
                              hipFuncAttributeMaxDynamicSharedMemorySize, (int)shb);
    chol_kernel<<<dim3(B_), blk, shb, stream>>>(G, logdet_arr);
    finalize_kernel<<<dim3(1), dim3(1), 0, stream>>>(sum_kp, logdet_arr, out);
}

// Round 6
// 882.758 us; speedup vs baseline: 2.3340x; 1.8497x over previous
//
#include <hip/hip_runtime.h>
#include <math.h>

#define B_   128
#define L_   197
#define C_   768
#define Nv_  196
#define Lt_  32
#define Ct_  512
#define H_   12
#define DH_  64
#define DPP_ 256
#define MTOK 25088   // B_*Nv_

typedef __attribute__((ext_vector_type(8))) short bf16x8_t;
typedef __attribute__((ext_vector_type(4))) float f32x4_t;

// split fp32 -> bf16 hi (truncate) + bf16 lo (RNE of remainder)
__device__ __forceinline__ void split_bf16(float a, unsigned &h, unsigned &l) {
    unsigned u = __float_as_uint(a);
    unsigned hu = u & 0xffff0000u;
    h = hu >> 16;
    float lf = a - __uint_as_float(hu);
    unsigned ul = __float_as_uint(lf);
    l = (ul + 0x7fffu + ((ul >> 16) & 1u)) >> 16;
}

// ---------------------------------------------------------------------------
// weight pre-split kernel
// ---------------------------------------------------------------------------
__global__ __launch_bounds__(256)
void split_kernel(const float* __restrict__ src, short* __restrict__ hi,
                  short* __restrict__ lo, int n)
{
    int i = blockIdx.x * 256 + threadIdx.x;
    if (i < n) {
        unsigned h, l;
        split_bf16(src[i], h, l);
        hi[i] = (short)h; lo[i] = (short)l;
    }
}

// ---------------------------------------------------------------------------
// 3-term split-bf16 MFMA GEMM: C[m][n] = sum_k A[m][k]*W[n][k] (+ bias[n])
//   A: fp32 (GATHER=1: vis_tok gather from x; else row-major stride Kd),
//      split to bf16 hi/lo during LDS staging (hidden under MFMA/LDS bound).
//   B: pre-split bf16 hi/lo arrays [N][Kd].
//   acc += Ah*Bh + Ah*Bl + Al*Bh  (fp32 MFMA accumulate, err ~2^-17)
// Tile 128x128, BK=32, 4 waves 2x2 (each 64x64 = 4x4 16x16 subtiles).
// LDS rows padded to 40 shorts (80 B): frag-read granule (5*row+p)%8 ->
// conflict-free ds_read_b128.
// EPI==1: MLP epilogue: gelu + W2 partial dots -> partials[m][24]
// ---------------------------------------------------------------------------
template<int GATHER, int EPI>
__global__ __launch_bounds__(256)
void mfma_gemm(const float* __restrict__ A, const short* __restrict__ Bh_g,
               const short* __restrict__ Bl_g, const float* __restrict__ bias,
               float* __restrict__ Cst, int Nst, int Kd,
               const float* __restrict__ W2, float* __restrict__ partials)
{
    __shared__ short Ah[128 * 40], Al[128 * 40], Bh[128 * 40], Bl[128 * 40];
    const int tid = threadIdx.x;
    const int m0 = blockIdx.x * 128, n0 = blockIdx.y * 128;
    const int l = tid & 63, wid = tid >> 6;
    const int wr = wid >> 1, wc = wid & 1;
    const int lr = l & 15, lq = l >> 4;

    // staging: thread covers rows {tid>>2, +64}, k-granule p8 = (tid&3)*8
    const int srow = tid >> 2;
    const int p8 = (tid & 3) << 3;
    const float* aptr[2]; const short* bhp[2]; const short* blp[2];
    int abase[2];
#pragma unroll
    for (int i = 0; i < 2; ++i) {
        int row = srow + i * 64;
        abase[i] = row * 40 + p8;
        int gr = m0 + row;
        if (GATHER) {
            int bb = gr / Nv_, n = gr - bb * Nv_;
            aptr[i] = A + ((size_t)(n + 1) * B_ + bb) * C_ + p8;
        } else {
            aptr[i] = A + (size_t)gr * Kd + p8;
        }
        int gc = n0 + row;
        bhp[i] = Bh_g + (size_t)gc * Kd + p8;
        blp[i] = Bl_g + (size_t)gc * Kd + p8;
    }

    f32x4_t acc[4][4];
#pragma unroll
    for (int m = 0; m < 4; ++m)
#pragma unroll
        for (int n = 0; n < 4; ++n) {
            acc[m][n][0] = 0.f; acc[m][n][1] = 0.f;
            acc[m][n][2] = 0.f; acc[m][n][3] = 0.f;
        }

    for (int k0 = 0; k0 < Kd; k0 += 32) {
#pragma unroll
        for (int i = 0; i < 2; ++i) {
            const float* s = aptr[i] + k0;
            float4 f0 = *(const float4*)s;
            float4 f1 = *(const float4*)(s + 4);
            float av[8] = {f0.x, f0.y, f0.z, f0.w, f1.x, f1.y, f1.z, f1.w};
            unsigned hv[8], lv[8];
#pragma unroll
            for (int j = 0; j < 8; ++j) split_bf16(av[j], hv[j], lv[j]);
            uint4 Hh, Ll;
            Hh.x = hv[0] | (hv[1] << 16); Hh.y = hv[2] | (hv[3] << 16);
            Hh.z = hv[4] | (hv[5] << 16); Hh.w = hv[6] | (hv[7] << 16);
            Ll.x = lv[0] | (lv[1] << 16); Ll.y = lv[2] | (lv[3] << 16);
            Ll.z = lv[4] | (lv[5] << 16); Ll.w = lv[6] | (lv[7] << 16);
            *(uint4*)&Ah[abase[i]] = Hh;
            *(uint4*)&Al[abase[i]] = Ll;
            *(uint4*)&Bh[abase[i]] = *(const uint4*)(bhp[i] + k0);
            *(uint4*)&Bl[abase[i]] = *(const uint4*)(blp[i] + k0);
        }
        __syncthreads();

        bf16x8_t ahf[4], alf[4], bhf[4], blf[4];
#pragma unroll
        for (int m = 0; m < 4; ++m) {
            int ro = (wr * 64 + m * 16 + lr) * 40 + lq * 8;
            ahf[m] = *(const bf16x8_t*)&Ah[ro];
            alf[m] = *(const bf16x8_t*)&Al[ro];
        }
#pragma unroll
        for (int n = 0; n < 4; ++n) {
            int ro = (wc * 64 + n * 16 + lr) * 40 + lq * 8;
            bhf[n] = *(const bf16x8_t*)&Bh[ro];
            blf[n] = *(const bf16x8_t*)&Bl[ro];
        }
#pragma unroll
        for (int m = 0; m < 4; ++m)
#pragma unroll
            for (int n = 0; n < 4; ++n) {
                acc[m][n] = __builtin_amdgcn_mfma_f32_16x16x32_bf16(ahf[m], bhf[n], acc[m][n], 0, 0, 0);
                acc[m][n] = __builtin_amdgcn_mfma_f32_16x16x32_bf16(ahf[m], blf[n], acc[m][n], 0, 0, 0);
                acc[m][n] = __builtin_amdgcn_mfma_f32_16x16x32_bf16(alf[m], bhf[n], acc[m][n], 0, 0, 0);
            }
        __syncthreads();
    }

    if constexpr (EPI == 0) {
#pragma unroll
        for (int n = 0; n < 4; ++n) {
            int col = n0 + wc * 64 + n * 16 + lr;
            float bv = bias ? bias[col] : 0.f;
#pragma unroll
            for (int m = 0; m < 4; ++m) {
                int rowb = m0 + wr * 64 + m * 16 + lq * 4;
#pragma unroll
                for (int r = 0; r < 4; ++r)
                    Cst[(size_t)(rowb + r) * Nst + col] = acc[m][n][r] + bv;
            }
        }
    } else {
        int coln[4]; float b1v[4], w20[4], w21[4];
#pragma unroll
        for (int n = 0; n < 4; ++n) {
            coln[n] = n0 + wc * 64 + n * 16 + lr;
            b1v[n] = bias[coln[n]];
            w20[n] = W2[coln[n]];
            w21[n] = W2[C_ + coln[n]];
        }
        const int pi = (blockIdx.y * 2 + wc) * 2;
#pragma unroll
        for (int m = 0; m < 4; ++m)
#pragma unroll
            for (int r = 0; r < 4; ++r) {
                float p0 = 0.f, p1 = 0.f;
#pragma unroll
                for (int n = 0; n < 4; ++n) {
                    float h = acc[m][n][r] + b1v[n];
                    float gl = h / (1.f + expf(-1.702f * h));
                    p0 = fmaf(gl, w20[n], p0);
                    p1 = fmaf(gl, w21[n], p1);
                }
#pragma unroll
                for (int off = 8; off; off >>= 1) {
                    p0 += __shfl_xor(p0, off, 16);
                    p1 += __shfl_xor(p1, off, 16);
                }
                if (lr == 0) {
                    int row = m0 + wr * 64 + m * 16 + lq * 4 + r;
                    partials[(size_t)row * 24 + pi + 0] = p0;
                    partials[(size_t)row * 24 + pi + 1] = p1;
                }
            }
    }
}

// ---------------------------------------------------------------------------
// fp32 NT GEMM (kept for the batched gram only). r5-verified.
// ---------------------------------------------------------------------------
template<int GATHER_A, int BOUNDS, int EPI>
__global__ __launch_bounds__(256)
void gemm_nt(const float* __restrict__ A, const float* __restrict__ Bm,
             const float* __restrict__ bias, float* __restrict__ C,
             int M, int N, int K, float scale,
             long strideA, long strideC,
             const float* __restrict__ W2, float* __restrict__ partials)
{
    __shared__ float As[16][132];
    __shared__ float Bs[16][132];
    const int tid = threadIdx.x;
    const int tx = tid & 15, ty = tid >> 4;
    const int m0 = blockIdx.x * 128, n0 = blockIdx.y * 128;
    const int bz = blockIdx.z;
    const float* Ab = A  + (size_t)bz * strideA;
    const float* Bb = Bm + (size_t)bz * strideA;
    float* Cb = C + (size_t)bz * strideC;

    const int lrow = tid >> 2;
    const int lk   = (tid & 3) << 2;

    const float* aptr[2]; const float* bptr[2];
    bool aval[2], bval[2];
#pragma unroll
    for (int Lq = 0; Lq < 2; ++Lq) {
        int row = lrow + Lq * 64;
        int gr = m0 + row;
        aval[Lq] = (!BOUNDS) || (gr < M);
        aptr[Lq] = Ab + (size_t)(aval[Lq] ? gr : 0) * K + lk;
        int gc = n0 + row;
        bval[Lq] = (!BOUNDS) || (gc < N);
        bptr[Lq] = Bb + (size_t)(bval[Lq] ? gc : 0) * K + lk;
    }

    float acc[8][8];
#pragma unroll
    for (int r = 0; r < 8; ++r)
#pragma unroll
        for (int c = 0; c < 8; ++c) acc[r][c] = 0.f;

    for (int k0 = 0; k0 < K; k0 += 16) {
#pragma unroll
        for (int Lq = 0; Lq < 2; ++Lq) {
            int row = lrow + Lq * 64;
            float4 va = aval[Lq] ? *(const float4*)(aptr[Lq] + k0)
                                 : make_float4(0.f, 0.f, 0.f, 0.f);
            As[lk+0][row] = va.x; As[lk+1][row] = va.y;
            As[lk+2][row] = va.z; As[lk+3][row] = va.w;
            float4 vb = bval[Lq] ? *(const float4*)(bptr[Lq] + k0)
                                 : make_float4(0.f, 0.f, 0.f, 0.f);
            Bs[lk+0][row] = vb.x; Bs[lk+1][row] = vb.y;
            Bs[lk+2][row] = vb.z; Bs[lk+3][row] = vb.w;
        }
        __syncthreads();
#pragma unroll
        for (int kk = 0; kk < 16; ++kk) {
            float a[8], bfr[8];
            *(float4*)&a[0]   = *(const float4*)&As[kk][ty * 8];
            *(float4*)&a[4]   = *(const float4*)&As[kk][ty * 8 + 4];
            *(float4*)&bfr[0] = *(const float4*)&Bs[kk][tx * 4];
            *(float4*)&bfr[4] = *(const float4*)&Bs[kk][64 + tx * 4];
#pragma unroll
            for (int r = 0; r < 8; ++r)
#pragma unroll
                for (int c = 0; c < 8; ++c)
                    acc[r][c] = fmaf(a[r], bfr[c], acc[r][c]);
        }
        __syncthreads();
    }

#pragma unroll
    for (int r = 0; r < 8; ++r) {
        int gr = m0 + ty * 8 + r;
        if (BOUNDS && gr >= M) continue;
#pragma unroll
        for (int half = 0; half < 2; ++half) {
            int gc = n0 + half * 64 + tx * 4;
#pragma unroll
            for (int c = 0; c < 4; ++c) {
                if (!BOUNDS || gc + c < N) {
                    float v = acc[r][half*4+c] * scale;
                    if (bias) v += bias[gc+c];
                    Cb[(size_t)gr * N + gc + c] = v;
                }
            }
        }
    }
}

// ---------------------------------------------------------------------------
// Attention per (b,h) — r3-verified version (LDS q/attn staging).
// fused = ctx + vis_tok written IN-PLACE over q.
// ---------------------------------------------------------------------------
__global__ __launch_bounds__(256)
void attn_kernel(const float* __restrict__ q, const float* __restrict__ k,
                 const float* __restrict__ v, const float* __restrict__ x,
                 float* __restrict__ fused)
{
    __shared__ float Ks[Lt_][DH_ + 1];
    __shared__ float Vs[Lt_][DH_ + 1];
    __shared__ float qs[4][DH_];
    __shared__ float as[4][Lt_];
    const int bh = blockIdx.x;
    const int b = bh / H_, h = bh - b * H_;
    const int tid = threadIdx.x;
    const int wv = tid >> 6, lane = tid & 63;

    for (int idx = tid; idx < Lt_ * 16; idx += 256) {
        int l = idx >> 4, dq = (idx & 15) << 2;
        size_t off = ((size_t)(b * Lt_ + l)) * C_ + h * DH_ + dq;
        float4 kv4 = *(const float4*)(k + off);
        Ks[l][dq] = kv4.x; Ks[l][dq + 1] = kv4.y; Ks[l][dq + 2] = kv4.z; Ks[l][dq + 3] = kv4.w;
        float4 vv4 = *(const float4*)(v + off);
        Vs[l][dq] = vv4.x; Vs[l][dq + 1] = vv4.y; Vs[l][dq + 2] = vv4.z; Vs[l][dq + 3] = vv4.w;
    }
    __syncthreads();

    for (int it = 0; it < 49; ++it) {
        int n = it * 4 + wv;
        size_t qoff = ((size_t)(b * Nv_ + n)) * C_ + h * DH_ + lane;
        float qv = q[qoff];
        qs[wv][lane] = qv;
        __syncthreads();
        float s;
        if (lane < Lt_) {
            s = 0.f;
#pragma unroll
            for (int d = 0; d < DH_; ++d) s = fmaf(qs[wv][d], Ks[lane][d], s);
            s *= 0.125f;
        } else s = -1e30f;
        float mx = s;
#pragma unroll
        for (int off = 16; off; off >>= 1) mx = fmaxf(mx, __shfl_xor(mx, off, 32));
        float p = (lane < Lt_) ? expf(s - mx) : 0.f;
        float sum = p;
#pragma unroll
        for (int off = 16; off; off >>= 1) sum += __shfl_xor(sum, off, 32);
        if (lane < Lt_) as[wv][lane] = p / sum;
        __syncthreads();
        float c = 0.f;
#pragma unroll
        for (int l = 0; l < Lt_; ++l) c = fmaf(as[wv][l], Vs[l][lane], c);
        float xv = x[((size_t)(n + 1) * B_ + b) * C_ + h * DH_ + lane];
        fused[qoff] = c + xv;
    }
}

// ---------------------------------------------------------------------------
// keep decisions: logits from partials[m][24] (+b2), gumbel, policy, keep_prob
// ---------------------------------------------------------------------------
__global__ __launch_bounds__(256)
void keep_kernel(const float* __restrict__ partials, const float* __restrict__ b2,
                 const float* __restrict__ gumbel, float* __restrict__ policy,
                 float* __restrict__ keep_prob)
{
    int m = blockIdx.x * 256 + threadIdx.x;
    int b = m / Nv_, n = m - b * Nv_;
    float l0 = b2[0], l1 = b2[1];
#pragma unroll
    for (int t = 0; t < 12; ++t) {
        l0 += partials[(size_t)m * 24 + t * 2 + 0];
        l1 += partials[(size_t)m * 24 + t * 2 + 1];
    }
    const float UHI = (float)(1.0 - 1e-6);
    float U0 = fminf(fmaxf(gumbel[(size_t)m * 2 + 0], 1e-6f), UHI);
    float U1 = fminf(fmaxf(gumbel[(size_t)m * 2 + 1], 1e-6f), UHI);
    float t0 = (float)log((double)U0);
    float g0 = -(float)log((double)(-t0));
    float t1 = (float)log((double)U1);
    float g1 = -(float)log((double)(-t1));
    float dlog = (l1 + g1) - (l0 + g0);
    float kp = 1.f / (1.f + expf(-dlog));
    policy[(size_t)b * 197 + 1 + n] = (dlog > 0.f) ? 1.f : 0.f;
    if (n == 0) policy[(size_t)b * 197] = 1.f;
    keep_prob[m] = kp;
}

__global__ __launch_bounds__(256)
void batch_reduce(const float* __restrict__ keep_prob, float* __restrict__ sum_kp)
{
    __shared__ float part[4];
    int b = blockIdx.x, tid = threadIdx.x;
    float vs = (tid < Nv_) ? keep_prob[(size_t)b * Nv_ + tid] : 0.f;
#pragma unroll
    for (int off = 32; off; off >>= 1) vs += __shfl_xor(vs, off, 64);
    if ((tid & 63) == 0) part[tid >> 6] = vs;
    __syncthreads();
    if (tid == 0) sum_kp[b] = part[0] + part[1] + part[2] + part[3];
}

__global__ __launch_bounds__(256)
void pw_scale(float* __restrict__ phi, const float* __restrict__ keep_prob,
              const float* __restrict__ sum_kp)
{
    int m = blockIdx.x * 4 + (threadIdx.x >> 6);
    int lane = threadIdx.x & 63;
    float4* row = (float4*)phi + (size_t)m * 64;
    float4 vv = row[lane];
    float ss = vv.x * vv.x + vv.y * vv.y + vv.z * vv.z + vv.w * vv.w;
#pragma unroll
    for (int off = 32; off; off >>= 1) ss += __shfl_xor(ss, off, 64);
    float nrm = fmaxf(sqrtf(ss), 1e-12f);
    int b = m / Nv_;
    float kp = keep_prob[m];
    float meanw = sum_kp[b] * (1.f / 196.f);
    float wn = fmaxf(kp / (meanw + 1e-12f), 1e-6f);
    float sc = sqrtf(wn) / nrm;
    vv.x *= sc; vv.y *= sc; vv.z *= sc; vv.w *= sc;
    row[lane] = vv;
}

// ---------------------------------------------------------------------------
// Per-batch blocked Cholesky logdet (r3-verified). Row stride 197.
// ---------------------------------------------------------------------------
#define LS_   197
#define PBS_  14

__global__ __launch_bounds__(256)
void chol_kernel(const float* __restrict__ G, float* __restrict__ logdet_arr)
{
    extern __shared__ float sm[];
    float* Am  = sm;
    float* col = sm + 196 * LS_;
    const int b = blockIdx.x, tid = threadIdx.x;
    const float* Gb = G + (size_t)b * Nv_ * Nv_;

    for (int idx = tid; idx < Nv_ * 49; idx += 256) {
        int i = idx / 49, c4 = (idx - i * 49) * 4;
        float4 v = *(const float4*)(Gb + (size_t)i * Nv_ + c4);
        if (i >= c4 && i < c4 + 4) (&v.x)[i - c4] += 1.00001f;
        float* dst = Am + i * LS_ + c4;
        dst[0] = v.x; dst[1] = v.y; dst[2] = v.z; dst[3] = v.w;
    }
    __syncthreads();

    float acc = 0.f;
    const int tx = tid & 15, ty = tid >> 4;

    for (int p = 0; p < Nv_ / PBS_; ++p) {
        const int j0 = p * PBS_;
        for (int jj = j0; jj < j0 + PBS_; ++jj) {
            float piv = Am[jj * LS_ + jj];
            if (tid == 0) acc += logf(piv);
            float inv = 1.f / sqrtf(piv);
            for (int i = jj + 1 + tid; i < Nv_; i += 256) {
                float v = Am[i * LS_ + jj] * inv;
                Am[i * LS_ + jj] = v;
                col[i] = v;
            }
            __syncthreads();
            for (int k = jj + 1; k < j0 + PBS_; ++k) {
                float ck = col[k];
                for (int i = k + tid; i < Nv_; i += 256)
                    Am[i * LS_ + k] = fmaf(-col[i], ck, Am[i * LS_ + k]);
            }
            __syncthreads();
        }
        const int j1 = j0 + PBS_;
        if (j1 >= Nv_) break;
        const int s = Nv_ - j1;
        const int nb = (s + 63) >> 6;
        for (int rb = 0; rb < nb; ++rb)
            for (int cb = 0; cb <= rb; ++cb) {
                const int i0 = j1 + rb * 64;
                const int k0 = j1 + cb * 64;
                float accs[4][4];
#pragma unroll
                for (int r = 0; r < 4; ++r)
#pragma unroll
                    for (int c = 0; c < 4; ++c) accs[r][c] = 0.f;
                float Li[4][PBS_];
#pragma unroll
                for (int r = 0; r < 4; ++r) {
                    int i = i0 + ty + 16 * r; if (i > 195) i = 195;
#pragma unroll
                    for (int t = 0; t < PBS_; ++t) Li[r][t] = Am[i * LS_ + j0 + t];
                }
#pragma unroll
                for (int t = 0; t < PBS_; ++t) {
                    float Lk[4];
#pragma unroll
                    for (int c = 0; c < 4; ++c) {
                        int kx = k0 + 4 * tx + c; if (kx > 195) kx = 195;
                        Lk[c] = Am[kx * LS_ + j0 + t];
                    }
#pragma unroll
                    for (int r = 0; r < 4; ++r)
#pragma unroll
                        for (int c = 0; c < 4; ++c)
                            accs[r][c] = fmaf(Li[r][t], Lk[c], accs[r][c]);
                }
#pragma unroll
                for (int r = 0; r < 4; ++r) {
                    int i = i0 + ty + 16 * r;
                    if (i < Nv_) {
#pragma unroll
                        for (int c = 0; c < 4; ++c) {
                            int kx = k0 + 4 * tx + c;
                            if (kx < Nv_) Am[i * LS_ + kx] -= accs[r][c];
                        }
                    }
                }
            }
        __syncthreads();
    }
    if (tid == 0) logdet_arr[b] = acc;
}

__global__ void finalize_kernel(const float* __restrict__ sum_kp,
                                const float* __restrict__ logdet_arr,
                                float* __restrict__ out)
{
    float tot = 0.f, ld = 0.f;
    for (int b = 0; b < B_; ++b) { tot += sum_kp[b]; ld += logdet_arr[b]; }
    float mean = tot * (1.f / 25088.f);
    float d = mean - 0.7f;
    out[25216] = d * d;
    out[25217] = -ld * (1.f / 128.f);
}

// ---------------------------------------------------------------------------
extern "C" void kernel_launch(void* const* d_in, const int* in_sizes, int n_in,
                              void* d_out, int out_size, void* d_ws, size_t ws_size,
                              hipStream_t stream)
{
    const float* x      = (const float*)d_in[0];
    const float* text   = (const float*)d_in[1];
    const float* gumbel = (const float*)d_in[2];
    const float* Wq     = (const float*)d_in[3];
    const float* bq     = (const float*)d_in[4];
    const float* Wk     = (const float*)d_in[5];
    const float* bk     = (const float*)d_in[6];
    const float* Wv     = (const float*)d_in[7];
    const float* bv     = (const float*)d_in[8];
    const float* W1     = (const float*)d_in[9];
    const float* b1     = (const float*)d_in[10];
    const float* W2     = (const float*)d_in[11];
    const float* b2     = (const float*)d_in[12];
    const float* Wdpp   = (const float*)d_in[13];
    float* out = (float*)d_out;

    float* ws = (float*)d_ws;
    float* q          = ws;                       // 19,267,584 f ; reused as G
    float* kbuf       = q + 19267584;             //  3,145,728
    float* vbuf       = kbuf + 3145728;           //  3,145,728
    float* phi        = vbuf + 3145728;           //  6,422,528
    float* partials   = phi + 6422528;            // 25088*24 = 602,112
    float* keep_prob  = partials + 602112;        //     25,088
    float* sum_kp     = keep_prob + 25088;        //        128
    float* logdet_arr = sum_kp + 128;             //        128
    float* G          = ws;                       // reuse q (dead after MLP)

    // bf16 weight-split region (16B-aligned: float prefix is 16B multiple)
    short* Wq_h = (short*)(logdet_arr + 128);     // 589,824 each
    short* Wq_l = Wq_h + 589824;
    short* W1_h = Wq_l + 589824;
    short* W1_l = W1_h + 589824;
    short* Wk_h = W1_l + 589824;                  // 393,216 each
    short* Wk_l = Wk_h + 393216;
    short* Wv_h = Wk_l + 393216;
    short* Wv_l = Wv_h + 393216;
    short* Wd_h = Wv_l + 393216;                  // 196,608 each
    short* Wd_l = Wd_h + 196608;

    dim3 blk(256);

    // weight pre-splits
    split_kernel<<<dim3(2304), blk, 0, stream>>>(Wq, Wq_h, Wq_l, 589824);
    split_kernel<<<dim3(2304), blk, 0, stream>>>(W1, W1_h, W1_l, 589824);
    split_kernel<<<dim3(1536), blk, 0, stream>>>(Wk, Wk_h, Wk_l, 393216);
    split_kernel<<<dim3(1536), blk, 0, stream>>>(Wv, Wv_h, Wv_l, 393216);
    split_kernel<<<dim3(768),  blk, 0, stream>>>(Wdpp, Wd_h, Wd_l, 196608);

    // k,v projections: M=4096, N=768, K=512
    mfma_gemm<0,0><<<dim3(32,6), blk, 0, stream>>>(text, Wk_h, Wk_l, bk, kbuf, 768, 512, nullptr, nullptr);
    mfma_gemm<0,0><<<dim3(32,6), blk, 0, stream>>>(text, Wv_h, Wv_l, bv, vbuf, 768, 512, nullptr, nullptr);
    // q projection (gathered vis_tok): M=25088, N=768, K=768
    mfma_gemm<1,0><<<dim3(196,6), blk, 0, stream>>>(x, Wq_h, Wq_l, bq, q, 768, 768, nullptr, nullptr);
    // attention + residual -> fused (in place over q)
    attn_kernel<<<dim3(B_*H_), blk, 0, stream>>>(q, kbuf, vbuf, x, q);
    // MLP: hmid=gelu(fused@W1^T+b1); logits partials via W2 in epilogue
    mfma_gemm<0,1><<<dim3(196,6), blk, 0, stream>>>(q, W1_h, W1_l, b1, nullptr, 768, 768, W2, partials);
    // keep decisions + policy
    keep_kernel<<<dim3(98), blk, 0, stream>>>(partials, b2, gumbel, out, keep_prob);
    batch_reduce<<<dim3(B_), blk, 0, stream>>>(keep_prob, sum_kp);
    // phi projection (gathered vis_tok): M=25088, N=256, K=768
    mfma_gemm<1,0><<<dim3(196,2), blk, 0, stream>>>(x, Wd_h, Wd_l, nullptr, phi, 256, 768, nullptr, nullptr);
    // normalize + weight (rel==1 analytically)
    pw_scale<<<dim3(6272), blk, 0, stream>>>(phi, keep_prob, sum_kp);
    // per-batch gram (fp32)
    gemm_nt<0,1,0><<<dim3(2,2,B_), blk, 0, stream>>>(phi, phi, nullptr, G, Nv_, Nv_, 256,
                                                     1.0f/(256.0f*196.0f*0.01f),
                                                     (long)Nv_*256, (long)Nv_*Nv_, nullptr, nullptr);
    // per-batch Cholesky logdet
    size_t shb = (size_t)(Nv_ * LS_ + Nv_) * sizeof(float);
    (void)hipFuncSetAttribute((const void*)chol_kernel,
                              hipFuncAttributeMaxDynamicSharedMemorySize, (int)shb);
    chol_kernel<<<dim3(B_), blk, shb, stream>>>(G, logdet_arr);
    finalize_kernel<<<dim3(1), dim3(1), 0, stream>>>(sum_kp, logdet_arr, out);
}

// Round 7
// 843.991 us; speedup vs baseline: 2.4412x; 1.0459x over previous
//
#include <hip/hip_runtime.h>
#include <math.h>

#define B_   128
#define L_   197
#define C_   768
#define Nv_  196
#define Lt_  32
#define Ct_  512
#define H_   12
#define DH_  64
#define DPP_ 256
#define MTOK 25088   // B_*Nv_

typedef __attribute__((ext_vector_type(8))) short bf16x8_t;
typedef __attribute__((ext_vector_type(4))) float f32x4_t;

// split fp32 -> bf16 hi (truncate) + bf16 lo (RNE of remainder)
__device__ __forceinline__ void split_bf16(float a, unsigned &h, unsigned &l) {
    unsigned u = __float_as_uint(a);
    unsigned hu = u & 0xffff0000u;
    h = hu >> 16;
    float lf = a - __uint_as_float(hu);
    unsigned ul = __float_as_uint(lf);
    l = (ul + 0x7fffu + ((ul >> 16) & 1u)) >> 16;
}

// ---------------------------------------------------------------------------
// weight pre-split kernel
// ---------------------------------------------------------------------------
__global__ __launch_bounds__(256)
void split_kernel(const float* __restrict__ src, short* __restrict__ hi,
                  short* __restrict__ lo, int n)
{
    int i = blockIdx.x * 256 + threadIdx.x;
    if (i < n) {
        unsigned h, l;
        split_bf16(src[i], h, l);
        hi[i] = (short)h; lo[i] = (short)l;
    }
}

// ---------------------------------------------------------------------------
// 3-term split-bf16 MFMA GEMM (r6-verified): C = A*W^T (+bias)
// acc += Ah*Bh + Ah*Bl + Al*Bh  (fp32 MFMA accumulate, err ~2^-17)
// ---------------------------------------------------------------------------
template<int GATHER, int EPI>
__global__ __launch_bounds__(256)
void mfma_gemm(const float* __restrict__ A, const short* __restrict__ Bh_g,
               const short* __restrict__ Bl_g, const float* __restrict__ bias,
               float* __restrict__ Cst, int Nst, int Kd,
               const float* __restrict__ W2, float* __restrict__ partials)
{
    __shared__ short Ah[128 * 40], Al[128 * 40], Bh[128 * 40], Bl[128 * 40];
    const int tid = threadIdx.x;
    const int m0 = blockIdx.x * 128, n0 = blockIdx.y * 128;
    const int l = tid & 63, wid = tid >> 6;
    const int wr = wid >> 1, wc = wid & 1;
    const int lr = l & 15, lq = l >> 4;

    const int srow = tid >> 2;
    const int p8 = (tid & 3) << 3;
    const float* aptr[2]; const short* bhp[2]; const short* blp[2];
    int abase[2];
#pragma unroll
    for (int i = 0; i < 2; ++i) {
        int row = srow + i * 64;
        abase[i] = row * 40 + p8;
        int gr = m0 + row;
        if (GATHER) {
            int bb = gr / Nv_, n = gr - bb * Nv_;
            aptr[i] = A + ((size_t)(n + 1) * B_ + bb) * C_ + p8;
        } else {
            aptr[i] = A + (size_t)gr * Kd + p8;
        }
        int gc = n0 + row;
        bhp[i] = Bh_g + (size_t)gc * Kd + p8;
        blp[i] = Bl_g + (size_t)gc * Kd + p8;
    }

    f32x4_t acc[4][4];
#pragma unroll
    for (int m = 0; m < 4; ++m)
#pragma unroll
        for (int n = 0; n < 4; ++n) {
            acc[m][n][0] = 0.f; acc[m][n][1] = 0.f;
            acc[m][n][2] = 0.f; acc[m][n][3] = 0.f;
        }

    for (int k0 = 0; k0 < Kd; k0 += 32) {
#pragma unroll
        for (int i = 0; i < 2; ++i) {
            const float* s = aptr[i] + k0;
            float4 f0 = *(const float4*)s;
            float4 f1 = *(const float4*)(s + 4);
            float av[8] = {f0.x, f0.y, f0.z, f0.w, f1.x, f1.y, f1.z, f1.w};
            unsigned hv[8], lv[8];
#pragma unroll
            for (int j = 0; j < 8; ++j) split_bf16(av[j], hv[j], lv[j]);
            uint4 Hh, Ll;
            Hh.x = hv[0] | (hv[1] << 16); Hh.y = hv[2] | (hv[3] << 16);
            Hh.z = hv[4] | (hv[5] << 16); Hh.w = hv[6] | (hv[7] << 16);
            Ll.x = lv[0] | (lv[1] << 16); Ll.y = lv[2] | (lv[3] << 16);
            Ll.z = lv[4] | (lv[5] << 16); Ll.w = lv[6] | (lv[7] << 16);
            *(uint4*)&Ah[abase[i]] = Hh;
            *(uint4*)&Al[abase[i]] = Ll;
            *(uint4*)&Bh[abase[i]] = *(const uint4*)(bhp[i] + k0);
            *(uint4*)&Bl[abase[i]] = *(const uint4*)(blp[i] + k0);
        }
        __syncthreads();

        bf16x8_t ahf[4], alf[4], bhf[4], blf[4];
#pragma unroll
        for (int m = 0; m < 4; ++m) {
            int ro = (wr * 64 + m * 16 + lr) * 40 + lq * 8;
            ahf[m] = *(const bf16x8_t*)&Ah[ro];
            alf[m] = *(const bf16x8_t*)&Al[ro];
        }
#pragma unroll
        for (int n = 0; n < 4; ++n) {
            int ro = (wc * 64 + n * 16 + lr) * 40 + lq * 8;
            bhf[n] = *(const bf16x8_t*)&Bh[ro];
            blf[n] = *(const bf16x8_t*)&Bl[ro];
        }
#pragma unroll
        for (int m = 0; m < 4; ++m)
#pragma unroll
            for (int n = 0; n < 4; ++n) {
                acc[m][n] = __builtin_amdgcn_mfma_f32_16x16x32_bf16(ahf[m], bhf[n], acc[m][n], 0, 0, 0);
                acc[m][n] = __builtin_amdgcn_mfma_f32_16x16x32_bf16(ahf[m], blf[n], acc[m][n], 0, 0, 0);
                acc[m][n] = __builtin_amdgcn_mfma_f32_16x16x32_bf16(alf[m], bhf[n], acc[m][n], 0, 0, 0);
            }
        __syncthreads();
    }

    if constexpr (EPI == 0) {
#pragma unroll
        for (int n = 0; n < 4; ++n) {
            int col = n0 + wc * 64 + n * 16 + lr;
            float bv = bias ? bias[col] : 0.f;
#pragma unroll
            for (int m = 0; m < 4; ++m) {
                int rowb = m0 + wr * 64 + m * 16 + lq * 4;
#pragma unroll
                for (int r = 0; r < 4; ++r)
                    Cst[(size_t)(rowb + r) * Nst + col] = acc[m][n][r] + bv;
            }
        }
    } else {
        int coln[4]; float b1v[4], w20[4], w21[4];
#pragma unroll
        for (int n = 0; n < 4; ++n) {
            coln[n] = n0 + wc * 64 + n * 16 + lr;
            b1v[n] = bias[coln[n]];
            w20[n] = W2[coln[n]];
            w21[n] = W2[C_ + coln[n]];
        }
        const int pi = (blockIdx.y * 2 + wc) * 2;
#pragma unroll
        for (int m = 0; m < 4; ++m)
#pragma unroll
            for (int r = 0; r < 4; ++r) {
                float p0 = 0.f, p1 = 0.f;
#pragma unroll
                for (int n = 0; n < 4; ++n) {
                    float h = acc[m][n][r] + b1v[n];
                    float gl = h / (1.f + expf(-1.702f * h));
                    p0 = fmaf(gl, w20[n], p0);
                    p1 = fmaf(gl, w21[n], p1);
                }
#pragma unroll
                for (int off = 8; off; off >>= 1) {
                    p0 += __shfl_xor(p0, off, 16);
                    p1 += __shfl_xor(p1, off, 16);
                }
                if (lr == 0) {
                    int row = m0 + wr * 64 + m * 16 + lq * 4 + r;
                    partials[(size_t)row * 24 + pi + 0] = p0;
                    partials[(size_t)row * 24 + pi + 1] = p1;
                }
            }
    }
}

// ---------------------------------------------------------------------------
// fp32 NT GEMM (batched gram only). r5-verified.
// ---------------------------------------------------------------------------
template<int GATHER_A, int BOUNDS, int EPI>
__global__ __launch_bounds__(256)
void gemm_nt(const float* __restrict__ A, const float* __restrict__ Bm,
             const float* __restrict__ bias, float* __restrict__ C,
             int M, int N, int K, float scale,
             long strideA, long strideC,
             const float* __restrict__ W2, float* __restrict__ partials)
{
    __shared__ float As[16][132];
    __shared__ float Bs[16][132];
    const int tid = threadIdx.x;
    const int tx = tid & 15, ty = tid >> 4;
    const int m0 = blockIdx.x * 128, n0 = blockIdx.y * 128;
    const int bz = blockIdx.z;
    const float* Ab = A  + (size_t)bz * strideA;
    const float* Bb = Bm + (size_t)bz * strideA;
    float* Cb = C + (size_t)bz * strideC;

    const int lrow = tid >> 2;
    const int lk   = (tid & 3) << 2;

    const float* aptr[2]; const float* bptr[2];
    bool aval[2], bval[2];
#pragma unroll
    for (int Lq = 0; Lq < 2; ++Lq) {
        int row = lrow + Lq * 64;
        int gr = m0 + row;
        aval[Lq] = (!BOUNDS) || (gr < M);
        aptr[Lq] = Ab + (size_t)(aval[Lq] ? gr : 0) * K + lk;
        int gc = n0 + row;
        bval[Lq] = (!BOUNDS) || (gc < N);
        bptr[Lq] = Bb + (size_t)(bval[Lq] ? gc : 0) * K + lk;
    }

    float acc[8][8];
#pragma unroll
    for (int r = 0; r < 8; ++r)
#pragma unroll
        for (int c = 0; c < 8; ++c) acc[r][c] = 0.f;

    for (int k0 = 0; k0 < K; k0 += 16) {
#pragma unroll
        for (int Lq = 0; Lq < 2; ++Lq) {
            int row = lrow + Lq * 64;
            float4 va = aval[Lq] ? *(const float4*)(aptr[Lq] + k0)
                                 : make_float4(0.f, 0.f, 0.f, 0.f);
            As[lk+0][row] = va.x; As[lk+1][row] = va.y;
            As[lk+2][row] = va.z; As[lk+3][row] = va.w;
            float4 vb = bval[Lq] ? *(const float4*)(bptr[Lq] + k0)
                                 : make_float4(0.f, 0.f, 0.f, 0.f);
            Bs[lk+0][row] = vb.x; Bs[lk+1][row] = vb.y;
            Bs[lk+2][row] = vb.z; Bs[lk+3][row] = vb.w;
        }
        __syncthreads();
#pragma unroll
        for (int kk = 0; kk < 16; ++kk) {
            float a[8], bfr[8];
            *(float4*)&a[0]   = *(const float4*)&As[kk][ty * 8];
            *(float4*)&a[4]   = *(const float4*)&As[kk][ty * 8 + 4];
            *(float4*)&bfr[0] = *(const float4*)&Bs[kk][tx * 4];
            *(float4*)&bfr[4] = *(const float4*)&Bs[kk][64 + tx * 4];
#pragma unroll
            for (int r = 0; r < 8; ++r)
#pragma unroll
                for (int c = 0; c < 8; ++c)
                    acc[r][c] = fmaf(a[r], bfr[c], acc[r][c]);
        }
        __syncthreads();
    }

#pragma unroll
    for (int r = 0; r < 8; ++r) {
        int gr = m0 + ty * 8 + r;
        if (BOUNDS && gr >= M) continue;
#pragma unroll
        for (int half = 0; half < 2; ++half) {
            int gc = n0 + half * 64 + tx * 4;
#pragma unroll
            for (int c = 0; c < 4; ++c) {
                if (!BOUNDS || gc + c < N) {
                    float v = acc[r][half*4+c] * scale;
                    if (bias) v += bias[gc+c];
                    Cb[(size_t)gr * N + gc + c] = v;
                }
            }
        }
    }
}

// ---------------------------------------------------------------------------
// Attention per (b,h): scores=qK^T/8, softmax over 32, ctx=attn@V,
// fused = ctx + vis_tok IN-PLACE over q.
// qs/as are WAVE-PRIVATE LDS slices -> no barriers in the loop (intra-wave
// LDS write->read ordering is compiler-inserted lgkmcnt). K rows padded to
// 68 dwords (16B-aligned -> ds_read_b128, uniform bank quads). V stays
// stride-65 scalar (conflict-free). FMA orders identical to r3/r6 (policy
// bits bit-exact).
// ---------------------------------------------------------------------------
__global__ __launch_bounds__(256)
void attn_kernel(const float* __restrict__ q, const float* __restrict__ k,
                 const float* __restrict__ v, const float* __restrict__ x,
                 float* __restrict__ fused)
{
    __shared__ float Ks[Lt_][DH_ + 4];
    __shared__ float Vs[Lt_][DH_ + 1];
    __shared__ float qs[4][DH_];
    __shared__ float as[4][Lt_];
    const int bh = blockIdx.x;
    const int b = bh / H_, h = bh - b * H_;
    const int tid = threadIdx.x;
    const int wv = tid >> 6, lane = tid & 63;

    for (int idx = tid; idx < Lt_ * 16; idx += 256) {  // 512 float4
        int l = idx >> 4, dq = (idx & 15) << 2;
        size_t off = ((size_t)(b * Lt_ + l)) * C_ + h * DH_ + dq;
        float4 kv4 = *(const float4*)(k + off);
        Ks[l][dq] = kv4.x; Ks[l][dq + 1] = kv4.y; Ks[l][dq + 2] = kv4.z; Ks[l][dq + 3] = kv4.w;
        float4 vv4 = *(const float4*)(v + off);
        Vs[l][dq] = vv4.x; Vs[l][dq + 1] = vv4.y; Vs[l][dq + 2] = vv4.z; Vs[l][dq + 3] = vv4.w;
    }
    __syncthreads();

    for (int it = 0; it < 49; ++it) {
        int n = it * 4 + wv;   // always < 196
        size_t qoff = ((size_t)(b * Nv_ + n)) * C_ + h * DH_ + lane;
        float qv = q[qoff];
        qs[wv][lane] = qv;          // wave-private; lgkmcnt orders the reads
        float s;
        if (lane < Lt_) {
            s = 0.f;
#pragma unroll
            for (int d4 = 0; d4 < DH_; d4 += 4) {
                float4 q4 = *(const float4*)&qs[wv][d4];   // broadcast read
                float4 k4 = *(const float4*)&Ks[lane][d4]; // b128, aligned
                s = fmaf(q4.x, k4.x, s);
                s = fmaf(q4.y, k4.y, s);
                s = fmaf(q4.z, k4.z, s);
                s = fmaf(q4.w, k4.w, s);
            }
            s *= 0.125f;
        } else s = -1e30f;
        float mx = s;
#pragma unroll
        for (int off = 16; off; off >>= 1) mx = fmaxf(mx, __shfl_xor(mx, off, 32));
        float p = (lane < Lt_) ? expf(s - mx) : 0.f;
        float sum = p;
#pragma unroll
        for (int off = 16; off; off >>= 1) sum += __shfl_xor(sum, off, 32);
        if (lane < Lt_) as[wv][lane] = p / sum;   // wave-private
        float c = 0.f;
#pragma unroll
        for (int l4 = 0; l4 < Lt_; l4 += 4) {
            float4 a4 = *(const float4*)&as[wv][l4];       // broadcast read
            c = fmaf(a4.x, Vs[l4 + 0][lane], c);
            c = fmaf(a4.y, Vs[l4 + 1][lane], c);
            c = fmaf(a4.z, Vs[l4 + 2][lane], c);
            c = fmaf(a4.w, Vs[l4 + 3][lane], c);
        }
        float xv = x[((size_t)(n + 1) * B_ + b) * C_ + h * DH_ + lane];
        fused[qoff] = c + xv;
    }
}

// ---------------------------------------------------------------------------
// keep decisions: logits from partials[m][24] (+b2), gumbel, policy, keep_prob
// ---------------------------------------------------------------------------
__global__ __launch_bounds__(256)
void keep_kernel(const float* __restrict__ partials, const float* __restrict__ b2,
                 const float* __restrict__ gumbel, float* __restrict__ policy,
                 float* __restrict__ keep_prob)
{
    int m = blockIdx.x * 256 + threadIdx.x;
    int b = m / Nv_, n = m - b * Nv_;
    float l0 = b2[0], l1 = b2[1];
#pragma unroll
    for (int t = 0; t < 12; ++t) {
        l0 += partials[(size_t)m * 24 + t * 2 + 0];
        l1 += partials[(size_t)m * 24 + t * 2 + 1];
    }
    const float UHI = (float)(1.0 - 1e-6);
    float U0 = fminf(fmaxf(gumbel[(size_t)m * 2 + 0], 1e-6f), UHI);
    float U1 = fminf(fmaxf(gumbel[(size_t)m * 2 + 1], 1e-6f), UHI);
    float t0 = (float)log((double)U0);
    float g0 = -(float)log((double)(-t0));
    float t1 = (float)log((double)U1);
    float g1 = -(float)log((double)(-t1));
    float dlog = (l1 + g1) - (l0 + g0);
    float kp = 1.f / (1.f + expf(-dlog));
    policy[(size_t)b * 197 + 1 + n] = (dlog > 0.f) ? 1.f : 0.f;
    if (n == 0) policy[(size_t)b * 197] = 1.f;
    keep_prob[m] = kp;
}

__global__ __launch_bounds__(256)
void batch_reduce(const float* __restrict__ keep_prob, float* __restrict__ sum_kp)
{
    __shared__ float part[4];
    int b = blockIdx.x, tid = threadIdx.x;
    float vs = (tid < Nv_) ? keep_prob[(size_t)b * Nv_ + tid] : 0.f;
#pragma unroll
    for (int off = 32; off; off >>= 1) vs += __shfl_xor(vs, off, 64);
    if ((tid & 63) == 0) part[tid >> 6] = vs;
    __syncthreads();
    if (tid == 0) sum_kp[b] = part[0] + part[1] + part[2] + part[3];
}

__global__ __launch_bounds__(256)
void pw_scale(float* __restrict__ phi, const float* __restrict__ keep_prob,
              const float* __restrict__ sum_kp)
{
    int m = blockIdx.x * 4 + (threadIdx.x >> 6);
    int lane = threadIdx.x & 63;
    float4* row = (float4*)phi + (size_t)m * 64;
    float4 vv = row[lane];
    float ss = vv.x * vv.x + vv.y * vv.y + vv.z * vv.z + vv.w * vv.w;
#pragma unroll
    for (int off = 32; off; off >>= 1) ss += __shfl_xor(ss, off, 64);
    float nrm = fmaxf(sqrtf(ss), 1e-12f);
    int b = m / Nv_;
    float kp = keep_prob[m];
    float meanw = sum_kp[b] * (1.f / 196.f);
    float wn = fmaxf(kp / (meanw + 1e-12f), 1e-6f);
    float sc = sqrtf(wn) / nrm;
    vv.x *= sc; vv.y *= sc; vv.z *= sc; vv.w *= sc;
    row[lane] = vv;
}

// ---------------------------------------------------------------------------
// Per-batch blocked Cholesky logdet (r3-verified). Row stride 197.
// ---------------------------------------------------------------------------
#define LS_   197
#define PBS_  14

__global__ __launch_bounds__(256)
void chol_kernel(const float* __restrict__ G, float* __restrict__ logdet_arr)
{
    extern __shared__ float sm[];
    float* Am  = sm;
    float* col = sm + 196 * LS_;
    const int b = blockIdx.x, tid = threadIdx.x;
    const float* Gb = G + (size_t)b * Nv_ * Nv_;

    for (int idx = tid; idx < Nv_ * 49; idx += 256) {
        int i = idx / 49, c4 = (idx - i * 49) * 4;
        float4 v = *(const float4*)(Gb + (size_t)i * Nv_ + c4);
        if (i >= c4 && i < c4 + 4) (&v.x)[i - c4] += 1.00001f;
        float* dst = Am + i * LS_ + c4;
        dst[0] = v.x; dst[1] = v.y; dst[2] = v.z; dst[3] = v.w;
    }
    __syncthreads();

    float acc = 0.f;
    const int tx = tid & 15, ty = tid >> 4;

    for (int p = 0; p < Nv_ / PBS_; ++p) {
        const int j0 = p * PBS_;
        for (int jj = j0; jj < j0 + PBS_; ++jj) {
            float piv = Am[jj * LS_ + jj];
            if (tid == 0) acc += logf(piv);
            float inv = 1.f / sqrtf(piv);
            for (int i = jj + 1 + tid; i < Nv_; i += 256) {
                float v = Am[i * LS_ + jj] * inv;
                Am[i * LS_ + jj] = v;
                col[i] = v;
            }
            __syncthreads();
            for (int k = jj + 1; k < j0 + PBS_; ++k) {
                float ck = col[k];
                for (int i = k + tid; i < Nv_; i += 256)
                    Am[i * LS_ + k] = fmaf(-col[i], ck, Am[i * LS_ + k]);
            }
            __syncthreads();
        }
        const int j1 = j0 + PBS_;
        if (j1 >= Nv_) break;
        const int s = Nv_ - j1;
        const int nb = (s + 63) >> 6;
        for (int rb = 0; rb < nb; ++rb)
            for (int cb = 0; cb <= rb; ++cb) {
                const int i0 = j1 + rb * 64;
                const int k0 = j1 + cb * 64;
                float accs[4][4];
#pragma unroll
                for (int r = 0; r < 4; ++r)
#pragma unroll
                    for (int c = 0; c < 4; ++c) accs[r][c] = 0.f;
                float Li[4][PBS_];
#pragma unroll
                for (int r = 0; r < 4; ++r) {
                    int i = i0 + ty + 16 * r; if (i > 195) i = 195;
#pragma unroll
                    for (int t = 0; t < PBS_; ++t) Li[r][t] = Am[i * LS_ + j0 + t];
                }
#pragma unroll
                for (int t = 0; t < PBS_; ++t) {
                    float Lk[4];
#pragma unroll
                    for (int c = 0; c < 4; ++c) {
                        int kx = k0 + 4 * tx + c; if (kx > 195) kx = 195;
                        Lk[c] = Am[kx * LS_ + j0 + t];
                    }
#pragma unroll
                    for (int r = 0; r < 4; ++r)
#pragma unroll
                        for (int c = 0; c < 4; ++c)
                            accs[r][c] = fmaf(Li[r][t], Lk[c], accs[r][c]);
                }
#pragma unroll
                for (int r = 0; r < 4; ++r) {
                    int i = i0 + ty + 16 * r;
                    if (i < Nv_) {
#pragma unroll
                        for (int c = 0; c < 4; ++c) {
                            int kx = k0 + 4 * tx + c;
                            if (kx < Nv_) Am[i * LS_ + kx] -= accs[r][c];
                        }
                    }
                }
            }
        __syncthreads();
    }
    if (tid == 0) logdet_arr[b] = acc;
}

__global__ void finalize_kernel(const float* __restrict__ sum_kp,
                                const float* __restrict__ logdet_arr,
                                float* __restrict__ out)
{
    float tot = 0.f, ld = 0.f;
    for (int b = 0; b < B_; ++b) { tot += sum_kp[b]; ld += logdet_arr[b]; }
    float mean = tot * (1.f / 25088.f);
    float d = mean - 0.7f;
    out[25216] = d * d;
    out[25217] = -ld * (1.f / 128.f);
}

// ---------------------------------------------------------------------------
extern "C" void kernel_launch(void* const* d_in, const int* in_sizes, int n_in,
                              void* d_out, int out_size, void* d_ws, size_t ws_size,
                              hipStream_t stream)
{
    const float* x      = (const float*)d_in[0];
    const float* text   = (const float*)d_in[1];
    const float* gumbel = (const float*)d_in[2];
    const float* Wq     = (const float*)d_in[3];
    const float* bq     = (const float*)d_in[4];
    const float* Wk     = (const float*)d_in[5];
    const float* bk     = (const float*)d_in[6];
    const float* Wv     = (const float*)d_in[7];
    const float* bv     = (const float*)d_in[8];
    const float* W1     = (const float*)d_in[9];
    const float* b1     = (const float*)d_in[10];
    const float* W2     = (const float*)d_in[11];
    const float* b2     = (const float*)d_in[12];
    const float* Wdpp   = (const float*)d_in[13];
    float* out = (float*)d_out;

    float* ws = (float*)d_ws;
    float* q          = ws;                       // 19,267,584 f ; reused as G
    float* kbuf       = q + 19267584;             //  3,145,728
    float* vbuf       = kbuf + 3145728;           //  3,145,728
    float* phi        = vbuf + 3145728;           //  6,422,528
    float* partials   = phi + 6422528;            // 25088*24 = 602,112
    float* keep_prob  = partials + 602112;        //     25,088
    float* sum_kp     = keep_prob + 25088;        //        128
    float* logdet_arr = sum_kp + 128;             //        128
    float* G          = ws;                       // reuse q (dead after MLP)

    short* Wq_h = (short*)(logdet_arr + 128);     // 589,824 each
    short* Wq_l = Wq_h + 589824;
    short* W1_h = Wq_l + 589824;
    short* W1_l = W1_h + 589824;
    short* Wk_h = W1_l + 589824;                  // 393,216 each
    short* Wk_l = Wk_h + 393216;
    short* Wv_h = Wk_l + 393216;
    short* Wv_l = Wv_h + 393216;
    short* Wd_h = Wv_l + 393216;                  // 196,608 each
    short* Wd_l = Wd_h + 196608;

    dim3 blk(256);

    split_kernel<<<dim3(2304), blk, 0, stream>>>(Wq, Wq_h, Wq_l, 589824);
    split_kernel<<<dim3(2304), blk, 0, stream>>>(W1, W1_h, W1_l, 589824);
    split_kernel<<<dim3(1536), blk, 0, stream>>>(Wk, Wk_h, Wk_l, 393216);
    split_kernel<<<dim3(1536), blk, 0, stream>>>(Wv, Wv_h, Wv_l, 393216);
    split_kernel<<<dim3(768),  blk, 0, stream>>>(Wdpp, Wd_h, Wd_l, 196608);

    mfma_gemm<0,0><<<dim3(32,6), blk, 0, stream>>>(text, Wk_h, Wk_l, bk, kbuf, 768, 512, nullptr, nullptr);
    mfma_gemm<0,0><<<dim3(32,6), blk, 0, stream>>>(text, Wv_h, Wv_l, bv, vbuf, 768, 512, nullptr, nullptr);
    mfma_gemm<1,0><<<dim3(196,6), blk, 0, stream>>>(x, Wq_h, Wq_l, bq, q, 768, 768, nullptr, nullptr);
    attn_kernel<<<dim3(B_*H_), blk, 0, stream>>>(q, kbuf, vbuf, x, q);
    mfma_gemm<0,1><<<dim3(196,6), blk, 0, stream>>>(q, W1_h, W1_l, b1, nullptr, 768, 768, W2, partials);
    keep_kernel<<<dim3(98), blk, 0, stream>>>(partials, b2, gumbel, out, keep_prob);
    batch_reduce<<<dim3(B_), blk, 0, stream>>>(keep_prob, sum_kp);
    mfma_gemm<1,0><<<dim3(196,2), blk, 0, stream>>>(x, Wd_h, Wd_l, nullptr, phi, 256, 768, nullptr, nullptr);
    pw_scale<<<dim3(6272), blk, 0, stream>>>(phi, keep_prob, sum_kp);
    gemm_nt<0,1,0><<<dim3(2,2,B_), blk, 0, stream>>>(phi, phi, nullptr, G, Nv_, Nv_, 256,
                                                     1.0f/(256.0f*196.0f*0.01f),
                                                     (long)Nv_*256, (long)Nv_*Nv_, nullptr, nullptr);
    size_t shb = (size_t)(Nv_ * LS_ + Nv_) * sizeof(float);
    (void)hipFuncSetAttribute((const void*)chol_kernel,
                              hipFuncAttributeMaxDynamicSharedMemorySize, (int)shb);
    chol_kernel<<<dim3(B_), blk, shb, stream>>>(G, logdet_arr);
    finalize_kernel<<<dim3(1), dim3(1), 0, stream>>>(sum_kp, logdet_arr, out);
}

// Round 8
// 767.155 us; speedup vs baseline: 2.6857x; 1.1002x over previous
//
#include <hip/hip_runtime.h>
#include <math.h>

#define B_   128
#define L_   197
#define C_   768
#define Nv_  196
#define Lt_  32
#define Ct_  512
#define H_   12
#define DH_  64
#define DPP_ 256
#define MTOK 25088   // B_*Nv_

typedef __attribute__((ext_vector_type(8))) short bf16x8_t;
typedef __attribute__((ext_vector_type(4))) float f32x4_t;

// split fp32 -> bf16 hi (truncate) + bf16 lo (RNE of remainder)
__device__ __forceinline__ void split_bf16(float a, unsigned &h, unsigned &l) {
    unsigned u = __float_as_uint(a);
    unsigned hu = u & 0xffff0000u;
    h = hu >> 16;
    float lf = a - __uint_as_float(hu);
    unsigned ul = __float_as_uint(lf);
    l = (ul + 0x7fffu + ((ul >> 16) & 1u)) >> 16;
}

// ---------------------------------------------------------------------------
// weight pre-split kernel
// ---------------------------------------------------------------------------
__global__ __launch_bounds__(256)
void split_kernel(const float* __restrict__ src, short* __restrict__ hi,
                  short* __restrict__ lo, int n)
{
    int i = blockIdx.x * 256 + threadIdx.x;
    if (i < n) {
        unsigned h, l;
        split_bf16(src[i], h, l);
        hi[i] = (short)h; lo[i] = (short)l;
    }
}

// ---------------------------------------------------------------------------
// 3-term split-bf16 MFMA GEMM (r6-verified): C = A*W^T (+bias)
// acc += Ah*Bh + Ah*Bl + Al*Bh  (fp32 MFMA accumulate, err ~2^-17)
// ---------------------------------------------------------------------------
template<int GATHER, int EPI>
__global__ __launch_bounds__(256)
void mfma_gemm(const float* __restrict__ A, const short* __restrict__ Bh_g,
               const short* __restrict__ Bl_g, const float* __restrict__ bias,
               float* __restrict__ Cst, int Nst, int Kd,
               const float* __restrict__ W2, float* __restrict__ partials)
{
    __shared__ short Ah[128 * 40], Al[128 * 40], Bh[128 * 40], Bl[128 * 40];
    const int tid = threadIdx.x;
    const int m0 = blockIdx.x * 128, n0 = blockIdx.y * 128;
    const int l = tid & 63, wid = tid >> 6;
    const int wr = wid >> 1, wc = wid & 1;
    const int lr = l & 15, lq = l >> 4;

    const int srow = tid >> 2;
    const int p8 = (tid & 3) << 3;
    const float* aptr[2]; const short* bhp[2]; const short* blp[2];
    int abase[2];
#pragma unroll
    for (int i = 0; i < 2; ++i) {
        int row = srow + i * 64;
        abase[i] = row * 40 + p8;
        int gr = m0 + row;
        if (GATHER) {
            int bb = gr / Nv_, n = gr - bb * Nv_;
            aptr[i] = A + ((size_t)(n + 1) * B_ + bb) * C_ + p8;
        } else {
            aptr[i] = A + (size_t)gr * Kd + p8;
        }
        int gc = n0 + row;
        bhp[i] = Bh_g + (size_t)gc * Kd + p8;
        blp[i] = Bl_g + (size_t)gc * Kd + p8;
    }

    f32x4_t acc[4][4];
#pragma unroll
    for (int m = 0; m < 4; ++m)
#pragma unroll
        for (int n = 0; n < 4; ++n) {
            acc[m][n][0] = 0.f; acc[m][n][1] = 0.f;
            acc[m][n][2] = 0.f; acc[m][n][3] = 0.f;
        }

    for (int k0 = 0; k0 < Kd; k0 += 32) {
#pragma unroll
        for (int i = 0; i < 2; ++i) {
            const float* s = aptr[i] + k0;
            float4 f0 = *(const float4*)s;
            float4 f1 = *(const float4*)(s + 4);
            float av[8] = {f0.x, f0.y, f0.z, f0.w, f1.x, f1.y, f1.z, f1.w};
            unsigned hv[8], lv[8];
#pragma unroll
            for (int j = 0; j < 8; ++j) split_bf16(av[j], hv[j], lv[j]);
            uint4 Hh, Ll;
            Hh.x = hv[0] | (hv[1] << 16); Hh.y = hv[2] | (hv[3] << 16);
            Hh.z = hv[4] | (hv[5] << 16); Hh.w = hv[6] | (hv[7] << 16);
            Ll.x = lv[0] | (lv[1] << 16); Ll.y = lv[2] | (lv[3] << 16);
            Ll.z = lv[4] | (lv[5] << 16); Ll.w = lv[6] | (lv[7] << 16);
            *(uint4*)&Ah[abase[i]] = Hh;
            *(uint4*)&Al[abase[i]] = Ll;
            *(uint4*)&Bh[abase[i]] = *(const uint4*)(bhp[i] + k0);
            *(uint4*)&Bl[abase[i]] = *(const uint4*)(blp[i] + k0);
        }
        __syncthreads();

        bf16x8_t ahf[4], alf[4], bhf[4], blf[4];
#pragma unroll
        for (int m = 0; m < 4; ++m) {
            int ro = (wr * 64 + m * 16 + lr) * 40 + lq * 8;
            ahf[m] = *(const bf16x8_t*)&Ah[ro];
            alf[m] = *(const bf16x8_t*)&Al[ro];
        }
#pragma unroll
        for (int n = 0; n < 4; ++n) {
            int ro = (wc * 64 + n * 16 + lr) * 40 + lq * 8;
            bhf[n] = *(const bf16x8_t*)&Bh[ro];
            blf[n] = *(const bf16x8_t*)&Bl[ro];
        }
#pragma unroll
        for (int m = 0; m < 4; ++m)
#pragma unroll
            for (int n = 0; n < 4; ++n) {
                acc[m][n] = __builtin_amdgcn_mfma_f32_16x16x32_bf16(ahf[m], bhf[n], acc[m][n], 0, 0, 0);
                acc[m][n] = __builtin_amdgcn_mfma_f32_16x16x32_bf16(ahf[m], blf[n], acc[m][n], 0, 0, 0);
                acc[m][n] = __builtin_amdgcn_mfma_f32_16x16x32_bf16(alf[m], bhf[n], acc[m][n], 0, 0, 0);
            }
        __syncthreads();
    }

    if constexpr (EPI == 0) {
#pragma unroll
        for (int n = 0; n < 4; ++n) {
            int col = n0 + wc * 64 + n * 16 + lr;
            float bv = bias ? bias[col] : 0.f;
#pragma unroll
            for (int m = 0; m < 4; ++m) {
                int rowb = m0 + wr * 64 + m * 16 + lq * 4;
#pragma unroll
                for (int r = 0; r < 4; ++r)
                    Cst[(size_t)(rowb + r) * Nst + col] = acc[m][n][r] + bv;
            }
        }
    } else {
        int coln[4]; float b1v[4], w20[4], w21[4];
#pragma unroll
        for (int n = 0; n < 4; ++n) {
            coln[n] = n0 + wc * 64 + n * 16 + lr;
            b1v[n] = bias[coln[n]];
            w20[n] = W2[coln[n]];
            w21[n] = W2[C_ + coln[n]];
        }
        const int pi = (blockIdx.y * 2 + wc) * 2;
#pragma unroll
        for (int m = 0; m < 4; ++m)
#pragma unroll
            for (int r = 0; r < 4; ++r) {
                float p0 = 0.f, p1 = 0.f;
#pragma unroll
                for (int n = 0; n < 4; ++n) {
                    float h = acc[m][n][r] + b1v[n];
                    float gl = h / (1.f + expf(-1.702f * h));
                    p0 = fmaf(gl, w20[n], p0);
                    p1 = fmaf(gl, w21[n], p1);
                }
#pragma unroll
                for (int off = 8; off; off >>= 1) {
                    p0 += __shfl_xor(p0, off, 16);
                    p1 += __shfl_xor(p1, off, 16);
                }
                if (lr == 0) {
                    int row = m0 + wr * 64 + m * 16 + lq * 4 + r;
                    partials[(size_t)row * 24 + pi + 0] = p0;
                    partials[(size_t)row * 24 + pi + 1] = p1;
                }
            }
    }
}

// ---------------------------------------------------------------------------
// fp32 NT GEMM (batched gram only). r5-verified.
// ---------------------------------------------------------------------------
template<int GATHER_A, int BOUNDS, int EPI>
__global__ __launch_bounds__(256)
void gemm_nt(const float* __restrict__ A, const float* __restrict__ Bm,
             const float* __restrict__ bias, float* __restrict__ C,
             int M, int N, int K, float scale,
             long strideA, long strideC,
             const float* __restrict__ W2, float* __restrict__ partials)
{
    __shared__ float As[16][132];
    __shared__ float Bs[16][132];
    const int tid = threadIdx.x;
    const int tx = tid & 15, ty = tid >> 4;
    const int m0 = blockIdx.x * 128, n0 = blockIdx.y * 128;
    const int bz = blockIdx.z;
    const float* Ab = A  + (size_t)bz * strideA;
    const float* Bb = Bm + (size_t)bz * strideA;
    float* Cb = C + (size_t)bz * strideC;

    const int lrow = tid >> 2;
    const int lk   = (tid & 3) << 2;

    const float* aptr[2]; const float* bptr[2];
    bool aval[2], bval[2];
#pragma unroll
    for (int Lq = 0; Lq < 2; ++Lq) {
        int row = lrow + Lq * 64;
        int gr = m0 + row;
        aval[Lq] = (!BOUNDS) || (gr < M);
        aptr[Lq] = Ab + (size_t)(aval[Lq] ? gr : 0) * K + lk;
        int gc = n0 + row;
        bval[Lq] = (!BOUNDS) || (gc < N);
        bptr[Lq] = Bb + (size_t)(bval[Lq] ? gc : 0) * K + lk;
    }

    float acc[8][8];
#pragma unroll
    for (int r = 0; r < 8; ++r)
#pragma unroll
        for (int c = 0; c < 8; ++c) acc[r][c] = 0.f;

    for (int k0 = 0; k0 < K; k0 += 16) {
#pragma unroll
        for (int Lq = 0; Lq < 2; ++Lq) {
            int row = lrow + Lq * 64;
            float4 va = aval[Lq] ? *(const float4*)(aptr[Lq] + k0)
                                 : make_float4(0.f, 0.f, 0.f, 0.f);
            As[lk+0][row] = va.x; As[lk+1][row] = va.y;
            As[lk+2][row] = va.z; As[lk+3][row] = va.w;
            float4 vb = bval[Lq] ? *(const float4*)(bptr[Lq] + k0)
                                 : make_float4(0.f, 0.f, 0.f, 0.f);
            Bs[lk+0][row] = vb.x; Bs[lk+1][row] = vb.y;
            Bs[lk+2][row] = vb.z; Bs[lk+3][row] = vb.w;
        }
        __syncthreads();
#pragma unroll
        for (int kk = 0; kk < 16; ++kk) {
            float a[8], bfr[8];
            *(float4*)&a[0]   = *(const float4*)&As[kk][ty * 8];
            *(float4*)&a[4]   = *(const float4*)&As[kk][ty * 8 + 4];
            *(float4*)&bfr[0] = *(const float4*)&Bs[kk][tx * 4];
            *(float4*)&bfr[4] = *(const float4*)&Bs[kk][64 + tx * 4];
#pragma unroll
            for (int r = 0; r < 8; ++r)
#pragma unroll
                for (int c = 0; c < 8; ++c)
                    acc[r][c] = fmaf(a[r], bfr[c], acc[r][c]);
        }
        __syncthreads();
    }

#pragma unroll
    for (int r = 0; r < 8; ++r) {
        int gr = m0 + ty * 8 + r;
        if (BOUNDS && gr >= M) continue;
#pragma unroll
        for (int half = 0; half < 2; ++half) {
            int gc = n0 + half * 64 + tx * 4;
#pragma unroll
            for (int c = 0; c < 4; ++c) {
                if (!BOUNDS || gc + c < N) {
                    float v = acc[r][half*4+c] * scale;
                    if (bias) v += bias[gc+c];
                    Cb[(size_t)gr * N + gc + c] = v;
                }
            }
        }
    }
}

// ---------------------------------------------------------------------------
// Attention per (b,h) — r7-verified (wave-private LDS, no in-loop barriers,
// vectorized K reads).
// ---------------------------------------------------------------------------
__global__ __launch_bounds__(256)
void attn_kernel(const float* __restrict__ q, const float* __restrict__ k,
                 const float* __restrict__ v, const float* __restrict__ x,
                 float* __restrict__ fused)
{
    __shared__ float Ks[Lt_][DH_ + 4];
    __shared__ float Vs[Lt_][DH_ + 1];
    __shared__ float qs[4][DH_];
    __shared__ float as[4][Lt_];
    const int bh = blockIdx.x;
    const int b = bh / H_, h = bh - b * H_;
    const int tid = threadIdx.x;
    const int wv = tid >> 6, lane = tid & 63;

    for (int idx = tid; idx < Lt_ * 16; idx += 256) {
        int l = idx >> 4, dq = (idx & 15) << 2;
        size_t off = ((size_t)(b * Lt_ + l)) * C_ + h * DH_ + dq;
        float4 kv4 = *(const float4*)(k + off);
        Ks[l][dq] = kv4.x; Ks[l][dq + 1] = kv4.y; Ks[l][dq + 2] = kv4.z; Ks[l][dq + 3] = kv4.w;
        float4 vv4 = *(const float4*)(v + off);
        Vs[l][dq] = vv4.x; Vs[l][dq + 1] = vv4.y; Vs[l][dq + 2] = vv4.z; Vs[l][dq + 3] = vv4.w;
    }
    __syncthreads();

    for (int it = 0; it < 49; ++it) {
        int n = it * 4 + wv;
        size_t qoff = ((size_t)(b * Nv_ + n)) * C_ + h * DH_ + lane;
        float qv = q[qoff];
        qs[wv][lane] = qv;
        float s;
        if (lane < Lt_) {
            s = 0.f;
#pragma unroll
            for (int d4 = 0; d4 < DH_; d4 += 4) {
                float4 q4 = *(const float4*)&qs[wv][d4];
                float4 k4 = *(const float4*)&Ks[lane][d4];
                s = fmaf(q4.x, k4.x, s);
                s = fmaf(q4.y, k4.y, s);
                s = fmaf(q4.z, k4.z, s);
                s = fmaf(q4.w, k4.w, s);
            }
            s *= 0.125f;
        } else s = -1e30f;
        float mx = s;
#pragma unroll
        for (int off = 16; off; off >>= 1) mx = fmaxf(mx, __shfl_xor(mx, off, 32));
        float p = (lane < Lt_) ? expf(s - mx) : 0.f;
        float sum = p;
#pragma unroll
        for (int off = 16; off; off >>= 1) sum += __shfl_xor(sum, off, 32);
        if (lane < Lt_) as[wv][lane] = p / sum;
        float c = 0.f;
#pragma unroll
        for (int l4 = 0; l4 < Lt_; l4 += 4) {
            float4 a4 = *(const float4*)&as[wv][l4];
            c = fmaf(a4.x, Vs[l4 + 0][lane], c);
            c = fmaf(a4.y, Vs[l4 + 1][lane], c);
            c = fmaf(a4.z, Vs[l4 + 2][lane], c);
            c = fmaf(a4.w, Vs[l4 + 3][lane], c);
        }
        float xv = x[((size_t)(n + 1) * B_ + b) * C_ + h * DH_ + lane];
        fused[qoff] = c + xv;
    }
}

// ---------------------------------------------------------------------------
// keep decisions: logits from partials[m][24] (+b2), gumbel, policy, keep_prob
// ---------------------------------------------------------------------------
__global__ __launch_bounds__(256)
void keep_kernel(const float* __restrict__ partials, const float* __restrict__ b2,
                 const float* __restrict__ gumbel, float* __restrict__ policy,
                 float* __restrict__ keep_prob)
{
    int m = blockIdx.x * 256 + threadIdx.x;
    int b = m / Nv_, n = m - b * Nv_;
    float l0 = b2[0], l1 = b2[1];
#pragma unroll
    for (int t = 0; t < 12; ++t) {
        l0 += partials[(size_t)m * 24 + t * 2 + 0];
        l1 += partials[(size_t)m * 24 + t * 2 + 1];
    }
    const float UHI = (float)(1.0 - 1e-6);
    float U0 = fminf(fmaxf(gumbel[(size_t)m * 2 + 0], 1e-6f), UHI);
    float U1 = fminf(fmaxf(gumbel[(size_t)m * 2 + 1], 1e-6f), UHI);
    float t0 = (float)log((double)U0);
    float g0 = -(float)log((double)(-t0));
    float t1 = (float)log((double)U1);
    float g1 = -(float)log((double)(-t1));
    float dlog = (l1 + g1) - (l0 + g0);
    float kp = 1.f / (1.f + expf(-dlog));
    policy[(size_t)b * 197 + 1 + n] = (dlog > 0.f) ? 1.f : 0.f;
    if (n == 0) policy[(size_t)b * 197] = 1.f;
    keep_prob[m] = kp;
}

__global__ __launch_bounds__(256)
void batch_reduce(const float* __restrict__ keep_prob, float* __restrict__ sum_kp)
{
    __shared__ float part[4];
    int b = blockIdx.x, tid = threadIdx.x;
    float vs = (tid < Nv_) ? keep_prob[(size_t)b * Nv_ + tid] : 0.f;
#pragma unroll
    for (int off = 32; off; off >>= 1) vs += __shfl_xor(vs, off, 64);
    if ((tid & 63) == 0) part[tid >> 6] = vs;
    __syncthreads();
    if (tid == 0) sum_kp[b] = part[0] + part[1] + part[2] + part[3];
}

__global__ __launch_bounds__(256)
void pw_scale(float* __restrict__ phi, const float* __restrict__ keep_prob,
              const float* __restrict__ sum_kp)
{
    int m = blockIdx.x * 4 + (threadIdx.x >> 6);
    int lane = threadIdx.x & 63;
    float4* row = (float4*)phi + (size_t)m * 64;
    float4 vv = row[lane];
    float ss = vv.x * vv.x + vv.y * vv.y + vv.z * vv.z + vv.w * vv.w;
#pragma unroll
    for (int off = 32; off; off >>= 1) ss += __shfl_xor(ss, off, 64);
    float nrm = fmaxf(sqrtf(ss), 1e-12f);
    int b = m / Nv_;
    float kp = keep_prob[m];
    float meanw = sum_kp[b] * (1.f / 196.f);
    float wn = fmaxf(kp / (meanw + 1e-12f), 1e-6f);
    float sc = sqrtf(wn) / nrm;
    vv.x *= sc; vv.y *= sc; vv.z *= sc; vv.w *= sc;
    row[lane] = vv;
}

// ---------------------------------------------------------------------------
// Per-batch blocked Cholesky logdet, panel-in-registers.
// Thread i owns panel row i: Rp[14] in VGPRs. Per column step jj, owner
// threads publish the RAW column colraw[jj][k]=Rp[jj]; after ONE barrier,
// every thread derives piv/inv/scaled column itself. No LDS RMW passes.
// Rounding & order identical to r7 (logdet bit-identical): inv=1/sqrtf(piv),
// lij=Rp[jj]*inv, lk=colraw*inv, fmaf(-lij,lk,Rp[k]).
// SYRK unchanged except Li hoisted out of the cb loop.
// ---------------------------------------------------------------------------
#define LS_   197
#define PBS_  14

__global__ __launch_bounds__(256)
void chol_kernel(const float* __restrict__ G, float* __restrict__ logdet_arr)
{
    extern __shared__ float sm[];
    float* Am  = sm;                          // 196 * 197
    float (*colraw)[PBS_] = (float(*)[PBS_])(sm + 196 * LS_);  // [14][14]
    const int b = blockIdx.x, tid = threadIdx.x;
    const float* Gb = G + (size_t)b * Nv_ * Nv_;

    for (int idx = tid; idx < Nv_ * 49; idx += 256) {
        int i = idx / 49, c4 = (idx - i * 49) * 4;
        float4 v = *(const float4*)(Gb + (size_t)i * Nv_ + c4);
        if (i >= c4 && i < c4 + 4) (&v.x)[i - c4] += 1.00001f;
        float* dst = Am + i * LS_ + c4;
        dst[0] = v.x; dst[1] = v.y; dst[2] = v.z; dst[3] = v.w;
    }
    __syncthreads();

    float acc = 0.f;
    const int tx = tid & 15, ty = tid >> 4;

    for (int p = 0; p < Nv_ / PBS_; ++p) {
        const int j0 = p * PBS_;
        const int j1 = j0 + PBS_;
        const int i = tid;                    // panel row owned by this thread
        const bool haveRow = (i >= j0 && i < Nv_);

        // load my panel row into registers
        float Rp[PBS_];
        if (haveRow) {
#pragma unroll
            for (int t = 0; t < PBS_; ++t) Rp[t] = Am[i * LS_ + j0 + t];
            if (i < j1) colraw[0][i - j0] = Rp[0];   // publish raw col 0
        }

        // ---- panel factorization: ONE barrier per column ----
        for (int jj = 0; jj < PBS_; ++jj) {
            __syncthreads();
            const int j = j0 + jj;
            float piv = colraw[jj][jj];
            if (tid == 0) acc += logf(piv);
            float inv = 1.f / sqrtf(piv);
            if (haveRow && i >= j) {
                float lij = Rp[jj] * inv;
                Rp[jj] = lij;
#pragma unroll
                for (int k = 0; k < PBS_; ++k) {
                    if (k > jj) {
                        float lk = colraw[jj][k] * inv;
                        Rp[k] = fmaf(-lij, lk, Rp[k]);
                    }
                }
                if (jj < PBS_ - 1 && i > j && i < j1)
                    colraw[jj + 1][i - j0] = Rp[jj + 1];
            }
        }

        // write back my row (SYRK and later panels read from Am)
        if (haveRow) {
#pragma unroll
            for (int t = 0; t < PBS_; ++t) Am[i * LS_ + j0 + t] = Rp[t];
        }
        __syncthreads();

        // ---- trailing SYRK (r7 structure, Li hoisted per rb) ----
        if (j1 >= Nv_) break;
        const int s = Nv_ - j1;
        const int nb = (s + 63) >> 6;
        for (int rb = 0; rb < nb; ++rb) {
            const int i0 = j1 + rb * 64;
            float Li[4][PBS_];
#pragma unroll
            for (int r = 0; r < 4; ++r) {
                int ir = i0 + ty + 16 * r; if (ir > 195) ir = 195;
#pragma unroll
                for (int t = 0; t < PBS_; ++t) Li[r][t] = Am[ir * LS_ + j0 + t];
            }
            for (int cb = 0; cb <= rb; ++cb) {
                const int k0 = j1 + cb * 64;
                float accs[4][4];
#pragma unroll
                for (int r = 0; r < 4; ++r)
#pragma unroll
                    for (int c = 0; c < 4; ++c) accs[r][c] = 0.f;
#pragma unroll
                for (int t = 0; t < PBS_; ++t) {
                    float Lk[4];
#pragma unroll
                    for (int c = 0; c < 4; ++c) {
                        int kx = k0 + 4 * tx + c; if (kx > 195) kx = 195;
                        Lk[c] = Am[kx * LS_ + j0 + t];
                    }
#pragma unroll
                    for (int r = 0; r < 4; ++r)
#pragma unroll
                        for (int c = 0; c < 4; ++c)
                            accs[r][c] = fmaf(Li[r][t], Lk[c], accs[r][c]);
                }
#pragma unroll
                for (int r = 0; r < 4; ++r) {
                    int ir = i0 + ty + 16 * r;
                    if (ir < Nv_) {
#pragma unroll
                        for (int c = 0; c < 4; ++c) {
                            int kx = k0 + 4 * tx + c;
                            if (kx < Nv_) Am[ir * LS_ + kx] -= accs[r][c];
                        }
                    }
                }
            }
        }
        __syncthreads();
    }
    if (tid == 0) logdet_arr[b] = acc;
}

__global__ void finalize_kernel(const float* __restrict__ sum_kp,
                                const float* __restrict__ logdet_arr,
                                float* __restrict__ out)
{
    float tot = 0.f, ld = 0.f;
    for (int b = 0; b < B_; ++b) { tot += sum_kp[b]; ld += logdet_arr[b]; }
    float mean = tot * (1.f / 25088.f);
    float d = mean - 0.7f;
    out[25216] = d * d;
    out[25217] = -ld * (1.f / 128.f);
}

// ---------------------------------------------------------------------------
extern "C" void kernel_launch(void* const* d_in, const int* in_sizes, int n_in,
                              void* d_out, int out_size, void* d_ws, size_t ws_size,
                              hipStream_t stream)
{
    const float* x      = (const float*)d_in[0];
    const float* text   = (const float*)d_in[1];
    const float* gumbel = (const float*)d_in[2];
    const float* Wq     = (const float*)d_in[3];
    const float* bq     = (const float*)d_in[4];
    const float* Wk     = (const float*)d_in[5];
    const float* bk     = (const float*)d_in[6];
    const float* Wv     = (const float*)d_in[7];
    const float* bv     = (const float*)d_in[8];
    const float* W1     = (const float*)d_in[9];
    const float* b1     = (const float*)d_in[10];
    const float* W2     = (const float*)d_in[11];
    const float* b2     = (const float*)d_in[12];
    const float* Wdpp   = (const float*)d_in[13];
    float* out = (float*)d_out;

    float* ws = (float*)d_ws;
    float* q          = ws;                       // 19,267,584 f ; reused as G
    float* kbuf       = q + 19267584;
    float* vbuf       = kbuf + 3145728;
    float* phi        = vbuf + 3145728;
    float* partials   = phi + 6422528;            // 25088*24
    float* keep_prob  = partials + 602112;
    float* sum_kp     = keep_prob + 25088;
    float* logdet_arr = sum_kp + 128;
    float* G          = ws;

    short* Wq_h = (short*)(logdet_arr + 128);
    short* Wq_l = Wq_h + 589824;
    short* W1_h = Wq_l + 589824;
    short* W1_l = W1_h + 589824;
    short* Wk_h = W1_l + 589824;
    short* Wk_l = Wk_h + 393216;
    short* Wv_h = Wk_l + 393216;
    short* Wv_l = Wv_h + 393216;
    short* Wd_h = Wv_l + 393216;
    short* Wd_l = Wd_h + 196608;

    dim3 blk(256);

    split_kernel<<<dim3(2304), blk, 0, stream>>>(Wq, Wq_h, Wq_l, 589824);
    split_kernel<<<dim3(2304), blk, 0, stream>>>(W1, W1_h, W1_l, 589824);
    split_kernel<<<dim3(1536), blk, 0, stream>>>(Wk, Wk_h, Wk_l, 393216);
    split_kernel<<<dim3(1536), blk, 0, stream>>>(Wv, Wv_h, Wv_l, 393216);
    split_kernel<<<dim3(768),  blk, 0, stream>>>(Wdpp, Wd_h, Wd_l, 196608);

    mfma_gemm<0,0><<<dim3(32,6), blk, 0, stream>>>(text, Wk_h, Wk_l, bk, kbuf, 768, 512, nullptr, nullptr);
    mfma_gemm<0,0><<<dim3(32,6), blk, 0, stream>>>(text, Wv_h, Wv_l, bv, vbuf, 768, 512, nullptr, nullptr);
    mfma_gemm<1,0><<<dim3(196,6), blk, 0, stream>>>(x, Wq_h, Wq_l, bq, q, 768, 768, nullptr, nullptr);
    attn_kernel<<<dim3(B_*H_), blk, 0, stream>>>(q, kbuf, vbuf, x, q);
    mfma_gemm<0,1><<<dim3(196,6), blk, 0, stream>>>(q, W1_h, W1_l, b1, nullptr, 768, 768, W2, partials);
    keep_kernel<<<dim3(98), blk, 0, stream>>>(partials, b2, gumbel, out, keep_prob);
    batch_reduce<<<dim3(B_), blk, 0, stream>>>(keep_prob, sum_kp);
    mfma_gemm<1,0><<<dim3(196,2), blk, 0, stream>>>(x, Wd_h, Wd_l, nullptr, phi, 256, 768, nullptr, nullptr);
    pw_scale<<<dim3(6272), blk, 0, stream>>>(phi, keep_prob, sum_kp);
    gemm_nt<0,1,0><<<dim3(2,2,B_), blk, 0, stream>>>(phi, phi, nullptr, G, Nv_, Nv_, 256,
                                                     1.0f/(256.0f*196.0f*0.01f),
                                                     (long)Nv_*256, (long)Nv_*Nv_, nullptr, nullptr);
    size_t shb = (size_t)(Nv_ * LS_ + Nv_) * sizeof(float);
    (void)hipFuncSetAttribute((const void*)chol_kernel,
                              hipFuncAttributeMaxDynamicSharedMemorySize, (int)shb);
    chol_kernel<<<dim3(B_), blk, shb, stream>>>(G, logdet_arr);
    finalize_kernel<<<dim3(1), dim3(1), 0, stream>>>(sum_kp, logdet_arr, out);
}

// Round 9
// 719.081 us; speedup vs baseline: 2.8653x; 1.0669x over previous
//
#include <hip/hip_runtime.h>
#include <math.h>

#define B_   128
#define L_   197
#define C_   768
#define Nv_  196
#define Lt_  32
#define Ct_  512
#define H_   12
#define DH_  64
#define DPP_ 256
#define MTOK 25088   // B_*Nv_

typedef __attribute__((ext_vector_type(8))) short bf16x8_t;
typedef __attribute__((ext_vector_type(4))) float f32x4_t;

// split fp32 -> bf16 hi (truncate) + bf16 lo (RNE of remainder)
__device__ __forceinline__ void split_bf16(float a, unsigned &h, unsigned &l) {
    unsigned u = __float_as_uint(a);
    unsigned hu = u & 0xffff0000u;
    h = hu >> 16;
    float lf = a - __uint_as_float(hu);
    unsigned ul = __float_as_uint(lf);
    l = (ul + 0x7fffu + ((ul >> 16) & 1u)) >> 16;
}

// ---------------------------------------------------------------------------
// fused weight pre-split (all 5 weights in one launch)
// ---------------------------------------------------------------------------
#define NWQ 589824
#define NWK 393216
#define NWD 196608
__global__ __launch_bounds__(256)
void split_all(const float* __restrict__ Wq, const float* __restrict__ W1,
               const float* __restrict__ Wk, const float* __restrict__ Wv,
               const float* __restrict__ Wd,
               short* __restrict__ Wq_h, short* __restrict__ Wq_l,
               short* __restrict__ W1_h, short* __restrict__ W1_l,
               short* __restrict__ Wk_h, short* __restrict__ Wk_l,
               short* __restrict__ Wv_h, short* __restrict__ Wv_l,
               short* __restrict__ Wd_h, short* __restrict__ Wd_l)
{
    int j = blockIdx.x * 256 + threadIdx.x;   // total 2,162,688 = 8448*256
    const float* src; short *hi, *lo;
    if (j < NWQ)                { src = Wq; hi = Wq_h; lo = Wq_l; }
    else if ((j -= NWQ) < NWQ)  { src = W1; hi = W1_h; lo = W1_l; }
    else if ((j -= NWQ) < NWK)  { src = Wk; hi = Wk_h; lo = Wk_l; }
    else if ((j -= NWK) < NWK)  { src = Wv; hi = Wv_h; lo = Wv_l; }
    else                        { j -= NWK;  src = Wd; hi = Wd_h; lo = Wd_l; }
    unsigned h, l;
    split_bf16(src[j], h, l);
    hi[j] = (short)h; lo[j] = (short)l;
}

// ---------------------------------------------------------------------------
// 3-term split-bf16 MFMA GEMM (r6-verified): C = A*W^T (+bias)
// acc += Ah*Bh + Ah*Bl + Al*Bh  (fp32 MFMA accumulate, err ~2^-17)
// blockIdx.z==1 selects the second (B,bias,C) set (merged k/v launch).
// ---------------------------------------------------------------------------
template<int GATHER, int EPI>
__global__ __launch_bounds__(256)
void mfma_gemm(const float* __restrict__ A, const short* __restrict__ Bh_g,
               const short* __restrict__ Bl_g, const float* __restrict__ bias,
               float* __restrict__ Cst, int Nst, int Kd,
               const float* __restrict__ W2, float* __restrict__ partials,
               const short* Bh2, const short* Bl2, const float* bias2,
               float* Cst2)
{
    if (blockIdx.z) { Bh_g = Bh2; Bl_g = Bl2; bias = bias2; Cst = Cst2; }
    __shared__ short Ah[128 * 40], Al[128 * 40], Bh[128 * 40], Bl[128 * 40];
    const int tid = threadIdx.x;
    const int m0 = blockIdx.x * 128, n0 = blockIdx.y * 128;
    const int l = tid & 63, wid = tid >> 6;
    const int wr = wid >> 1, wc = wid & 1;
    const int lr = l & 15, lq = l >> 4;

    const int srow = tid >> 2;
    const int p8 = (tid & 3) << 3;
    const float* aptr[2]; const short* bhp[2]; const short* blp[2];
    int abase[2];
#pragma unroll
    for (int i = 0; i < 2; ++i) {
        int row = srow + i * 64;
        abase[i] = row * 40 + p8;
        int gr = m0 + row;
        if (GATHER) {
            int bb = gr / Nv_, n = gr - bb * Nv_;
            aptr[i] = A + ((size_t)(n + 1) * B_ + bb) * C_ + p8;
        } else {
            aptr[i] = A + (size_t)gr * Kd + p8;
        }
        int gc = n0 + row;
        bhp[i] = Bh_g + (size_t)gc * Kd + p8;
        blp[i] = Bl_g + (size_t)gc * Kd + p8;
    }

    f32x4_t acc[4][4];
#pragma unroll
    for (int m = 0; m < 4; ++m)
#pragma unroll
        for (int n = 0; n < 4; ++n) {
            acc[m][n][0] = 0.f; acc[m][n][1] = 0.f;
            acc[m][n][2] = 0.f; acc[m][n][3] = 0.f;
        }

    for (int k0 = 0; k0 < Kd; k0 += 32) {
#pragma unroll
        for (int i = 0; i < 2; ++i) {
            const float* s = aptr[i] + k0;
            float4 f0 = *(const float4*)s;
            float4 f1 = *(const float4*)(s + 4);
            float av[8] = {f0.x, f0.y, f0.z, f0.w, f1.x, f1.y, f1.z, f1.w};
            unsigned hv[8], lv[8];
#pragma unroll
            for (int j = 0; j < 8; ++j) split_bf16(av[j], hv[j], lv[j]);
            uint4 Hh, Ll;
            Hh.x = hv[0] | (hv[1] << 16); Hh.y = hv[2] | (hv[3] << 16);
            Hh.z = hv[4] | (hv[5] << 16); Hh.w = hv[6] | (hv[7] << 16);
            Ll.x = lv[0] | (lv[1] << 16); Ll.y = lv[2] | (lv[3] << 16);
            Ll.z = lv[4] | (lv[5] << 16); Ll.w = lv[6] | (lv[7] << 16);
            *(uint4*)&Ah[abase[i]] = Hh;
            *(uint4*)&Al[abase[i]] = Ll;
            *(uint4*)&Bh[abase[i]] = *(const uint4*)(bhp[i] + k0);
            *(uint4*)&Bl[abase[i]] = *(const uint4*)(blp[i] + k0);
        }
        __syncthreads();

        bf16x8_t ahf[4], alf[4], bhf[4], blf[4];
#pragma unroll
        for (int m = 0; m < 4; ++m) {
            int ro = (wr * 64 + m * 16 + lr) * 40 + lq * 8;
            ahf[m] = *(const bf16x8_t*)&Ah[ro];
            alf[m] = *(const bf16x8_t*)&Al[ro];
        }
#pragma unroll
        for (int n = 0; n < 4; ++n) {
            int ro = (wc * 64 + n * 16 + lr) * 40 + lq * 8;
            bhf[n] = *(const bf16x8_t*)&Bh[ro];
            blf[n] = *(const bf16x8_t*)&Bl[ro];
        }
#pragma unroll
        for (int m = 0; m < 4; ++m)
#pragma unroll
            for (int n = 0; n < 4; ++n) {
                acc[m][n] = __builtin_amdgcn_mfma_f32_16x16x32_bf16(ahf[m], bhf[n], acc[m][n], 0, 0, 0);
                acc[m][n] = __builtin_amdgcn_mfma_f32_16x16x32_bf16(ahf[m], blf[n], acc[m][n], 0, 0, 0);
                acc[m][n] = __builtin_amdgcn_mfma_f32_16x16x32_bf16(alf[m], bhf[n], acc[m][n], 0, 0, 0);
            }
        __syncthreads();
    }

    if constexpr (EPI == 0) {
#pragma unroll
        for (int n = 0; n < 4; ++n) {
            int col = n0 + wc * 64 + n * 16 + lr;
            float bv = bias ? bias[col] : 0.f;
#pragma unroll
            for (int m = 0; m < 4; ++m) {
                int rowb = m0 + wr * 64 + m * 16 + lq * 4;
#pragma unroll
                for (int r = 0; r < 4; ++r)
                    Cst[(size_t)(rowb + r) * Nst + col] = acc[m][n][r] + bv;
            }
        }
    } else {
        int coln[4]; float b1v[4], w20[4], w21[4];
#pragma unroll
        for (int n = 0; n < 4; ++n) {
            coln[n] = n0 + wc * 64 + n * 16 + lr;
            b1v[n] = bias[coln[n]];
            w20[n] = W2[coln[n]];
            w21[n] = W2[C_ + coln[n]];
        }
        const int pi = (blockIdx.y * 2 + wc) * 2;
#pragma unroll
        for (int m = 0; m < 4; ++m)
#pragma unroll
            for (int r = 0; r < 4; ++r) {
                float p0 = 0.f, p1 = 0.f;
#pragma unroll
                for (int n = 0; n < 4; ++n) {
                    float h = acc[m][n][r] + b1v[n];
                    float gl = h / (1.f + expf(-1.702f * h));
                    p0 = fmaf(gl, w20[n], p0);
                    p1 = fmaf(gl, w21[n], p1);
                }
#pragma unroll
                for (int off = 8; off; off >>= 1) {
                    p0 += __shfl_xor(p0, off, 16);
                    p1 += __shfl_xor(p1, off, 16);
                }
                if (lr == 0) {
                    int row = m0 + wr * 64 + m * 16 + lq * 4 + r;
                    partials[(size_t)row * 24 + pi + 0] = p0;
                    partials[(size_t)row * 24 + pi + 1] = p1;
                }
            }
    }
}

// ---------------------------------------------------------------------------
// fp32 NT GEMM (batched gram only). r5-verified.
// ---------------------------------------------------------------------------
template<int GATHER_A, int BOUNDS, int EPI>
__global__ __launch_bounds__(256)
void gemm_nt(const float* __restrict__ A, const float* __restrict__ Bm,
             const float* __restrict__ bias, float* __restrict__ C,
             int M, int N, int K, float scale,
             long strideA, long strideC,
             const float* __restrict__ W2, float* __restrict__ partials)
{
    __shared__ float As[16][132];
    __shared__ float Bs[16][132];
    const int tid = threadIdx.x;
    const int tx = tid & 15, ty = tid >> 4;
    const int m0 = blockIdx.x * 128, n0 = blockIdx.y * 128;
    const int bz = blockIdx.z;
    const float* Ab = A  + (size_t)bz * strideA;
    const float* Bb = Bm + (size_t)bz * strideA;
    float* Cb = C + (size_t)bz * strideC;

    const int lrow = tid >> 2;
    const int lk   = (tid & 3) << 2;

    const float* aptr[2]; const float* bptr[2];
    bool aval[2], bval[2];
#pragma unroll
    for (int Lq = 0; Lq < 2; ++Lq) {
        int row = lrow + Lq * 64;
        int gr = m0 + row;
        aval[Lq] = (!BOUNDS) || (gr < M);
        aptr[Lq] = Ab + (size_t)(aval[Lq] ? gr : 0) * K + lk;
        int gc = n0 + row;
        bval[Lq] = (!BOUNDS) || (gc < N);
        bptr[Lq] = Bb + (size_t)(bval[Lq] ? gc : 0) * K + lk;
    }

    float acc[8][8];
#pragma unroll
    for (int r = 0; r < 8; ++r)
#pragma unroll
        for (int c = 0; c < 8; ++c) acc[r][c] = 0.f;

    for (int k0 = 0; k0 < K; k0 += 16) {
#pragma unroll
        for (int Lq = 0; Lq < 2; ++Lq) {
            int row = lrow + Lq * 64;
            float4 va = aval[Lq] ? *(const float4*)(aptr[Lq] + k0)
                                 : make_float4(0.f, 0.f, 0.f, 0.f);
            As[lk+0][row] = va.x; As[lk+1][row] = va.y;
            As[lk+2][row] = va.z; As[lk+3][row] = va.w;
            float4 vb = bval[Lq] ? *(const float4*)(bptr[Lq] + k0)
                                 : make_float4(0.f, 0.f, 0.f, 0.f);
            Bs[lk+0][row] = vb.x; Bs[lk+1][row] = vb.y;
            Bs[lk+2][row] = vb.z; Bs[lk+3][row] = vb.w;
        }
        __syncthreads();
#pragma unroll
        for (int kk = 0; kk < 16; ++kk) {
            float a[8], bfr[8];
            *(float4*)&a[0]   = *(const float4*)&As[kk][ty * 8];
            *(float4*)&a[4]   = *(const float4*)&As[kk][ty * 8 + 4];
            *(float4*)&bfr[0] = *(const float4*)&Bs[kk][tx * 4];
            *(float4*)&bfr[4] = *(const float4*)&Bs[kk][64 + tx * 4];
#pragma unroll
            for (int r = 0; r < 8; ++r)
#pragma unroll
                for (int c = 0; c < 8; ++c)
                    acc[r][c] = fmaf(a[r], bfr[c], acc[r][c]);
        }
        __syncthreads();
    }

#pragma unroll
    for (int r = 0; r < 8; ++r) {
        int gr = m0 + ty * 8 + r;
        if (BOUNDS && gr >= M) continue;
#pragma unroll
        for (int half = 0; half < 2; ++half) {
            int gc = n0 + half * 64 + tx * 4;
#pragma unroll
            for (int c = 0; c < 4; ++c) {
                if (!BOUNDS || gc + c < N) {
                    float v = acc[r][half*4+c] * scale;
                    if (bias) v += bias[gc+c];
                    Cb[(size_t)gr * N + gc + c] = v;
                }
            }
        }
    }
}

// ---------------------------------------------------------------------------
// Attention per (b,h): 2 rows per wave per iteration (independent FMA chains
// interleave -> 2x ILP) + q/x prefetch for the next iteration (hides ~600cy
// global latency under compute). Per-row op order identical to r7/r8 ->
// bit-identical output. Wave-private qs/as slices, no in-loop barriers.
// In-place fused-over-q safe: row p is prefetch-read at it and written at
// it+1 by the SAME wave (program order).
// ---------------------------------------------------------------------------
__global__ __launch_bounds__(256)
void attn_kernel(const float* __restrict__ q, const float* __restrict__ k,
                 const float* __restrict__ v, const float* __restrict__ x,
                 float* __restrict__ fused)
{
    __shared__ float Ks[Lt_][DH_ + 4];
    __shared__ float Vs[Lt_][DH_ + 1];
    __shared__ float qs[8][DH_];
    __shared__ float as[8][Lt_];
    const int bh = blockIdx.x;
    const int b = bh / H_, h = bh - b * H_;
    const int tid = threadIdx.x;
    const int wv = tid >> 6, lane = tid & 63;

    for (int idx = tid; idx < Lt_ * 16; idx += 256) {
        int l = idx >> 4, dq = (idx & 15) << 2;
        size_t off = ((size_t)(b * Lt_ + l)) * C_ + h * DH_ + dq;
        float4 kv4 = *(const float4*)(k + off);
        Ks[l][dq] = kv4.x; Ks[l][dq + 1] = kv4.y; Ks[l][dq + 2] = kv4.z; Ks[l][dq + 3] = kv4.w;
        float4 vv4 = *(const float4*)(v + off);
        Vs[l][dq] = vv4.x; Vs[l][dq + 1] = vv4.y; Vs[l][dq + 2] = vv4.z; Vs[l][dq + 3] = vv4.w;
    }
    __syncthreads();

    const size_t qbase = (size_t)b * Nv_ * C_ + h * DH_ + lane;
    const size_t xbase = (size_t)b * C_ + h * DH_ + lane;
    // q row n  -> q[qbase + n*C_]; x row n -> x[xbase + (n+1)*B_*C_]

    // prologue: rows for it=0
    float qv1 = q[qbase + (size_t)(wv) * C_];
    float qv2 = q[qbase + (size_t)(4 + wv) * C_];
    float xv1 = x[xbase + (size_t)(wv + 1) * B_ * C_];
    float xv2 = x[xbase + (size_t)(4 + wv + 1) * B_ * C_];

    for (int it = 0; it < 25; ++it) {
        const int m1 = it * 8 + wv;
        const int m2 = it * 8 + 4 + wv;
        const bool has2 = (m2 < Nv_);          // false only at it==24
        float cq1 = qv1, cq2 = qv2, cx1 = xv1, cx2 = xv2;
        if (it < 24) {                          // prefetch next iteration
            int p1 = m1 + 8, p2 = m2 + 8;
            qv1 = q[qbase + (size_t)p1 * C_];
            xv1 = x[xbase + (size_t)(p1 + 1) * B_ * C_];
            if (p2 < Nv_) {
                qv2 = q[qbase + (size_t)p2 * C_];
                xv2 = x[xbase + (size_t)(p2 + 1) * B_ * C_];
            }
        }
        qs[wv][lane] = cq1;
        qs[4 + wv][lane] = cq2;
        float s1, s2;
        if (lane < Lt_) {
            s1 = 0.f; s2 = 0.f;
#pragma unroll
            for (int d4 = 0; d4 < DH_; d4 += 4) {
                float4 k4  = *(const float4*)&Ks[lane][d4];
                float4 q4a = *(const float4*)&qs[wv][d4];
                float4 q4b = *(const float4*)&qs[4 + wv][d4];
                s1 = fmaf(q4a.x, k4.x, s1); s2 = fmaf(q4b.x, k4.x, s2);
                s1 = fmaf(q4a.y, k4.y, s1); s2 = fmaf(q4b.y, k4.y, s2);
                s1 = fmaf(q4a.z, k4.z, s1); s2 = fmaf(q4b.z, k4.z, s2);
                s1 = fmaf(q4a.w, k4.w, s1); s2 = fmaf(q4b.w, k4.w, s2);
            }
            s1 *= 0.125f; s2 *= 0.125f;
        } else { s1 = -1e30f; s2 = -1e30f; }
        float mx1 = s1, mx2 = s2;
#pragma unroll
        for (int off = 16; off; off >>= 1) {
            mx1 = fmaxf(mx1, __shfl_xor(mx1, off, 32));
            mx2 = fmaxf(mx2, __shfl_xor(mx2, off, 32));
        }
        float p1v = (lane < Lt_) ? expf(s1 - mx1) : 0.f;
        float p2v = (lane < Lt_) ? expf(s2 - mx2) : 0.f;
        float su1 = p1v, su2 = p2v;
#pragma unroll
        for (int off = 16; off; off >>= 1) {
            su1 += __shfl_xor(su1, off, 32);
            su2 += __shfl_xor(su2, off, 32);
        }
        if (lane < Lt_) {
            as[wv][lane] = p1v / su1;
            as[4 + wv][lane] = p2v / su2;
        }
        float c1 = 0.f, c2 = 0.f;
#pragma unroll
        for (int l4 = 0; l4 < Lt_; l4 += 4) {
            float4 a4a = *(const float4*)&as[wv][l4];
            float4 a4b = *(const float4*)&as[4 + wv][l4];
            float v0 = Vs[l4 + 0][lane], v1 = Vs[l4 + 1][lane];
            float v2 = Vs[l4 + 2][lane], v3 = Vs[l4 + 3][lane];
            c1 = fmaf(a4a.x, v0, c1); c2 = fmaf(a4b.x, v0, c2);
            c1 = fmaf(a4a.y, v1, c1); c2 = fmaf(a4b.y, v1, c2);
            c1 = fmaf(a4a.z, v2, c1); c2 = fmaf(a4b.z, v2, c2);
            c1 = fmaf(a4a.w, v3, c1); c2 = fmaf(a4b.w, v3, c2);
        }
        fused[qbase + (size_t)m1 * C_] = c1 + cx1;
        if (has2) fused[qbase + (size_t)m2 * C_] = c2 + cx2;
    }
}

// ---------------------------------------------------------------------------
// keep decisions: logits from partials[m][24] (+b2), gumbel, policy, keep_prob
// ---------------------------------------------------------------------------
__global__ __launch_bounds__(256)
void keep_kernel(const float* __restrict__ partials, const float* __restrict__ b2,
                 const float* __restrict__ gumbel, float* __restrict__ policy,
                 float* __restrict__ keep_prob)
{
    int m = blockIdx.x * 256 + threadIdx.x;
    int b = m / Nv_, n = m - b * Nv_;
    float l0 = b2[0], l1 = b2[1];
#pragma unroll
    for (int t = 0; t < 12; ++t) {
        l0 += partials[(size_t)m * 24 + t * 2 + 0];
        l1 += partials[(size_t)m * 24 + t * 2 + 1];
    }
    const float UHI = (float)(1.0 - 1e-6);
    float U0 = fminf(fmaxf(gumbel[(size_t)m * 2 + 0], 1e-6f), UHI);
    float U1 = fminf(fmaxf(gumbel[(size_t)m * 2 + 1], 1e-6f), UHI);
    float t0 = (float)log((double)U0);
    float g0 = -(float)log((double)(-t0));
    float t1 = (float)log((double)U1);
    float g1 = -(float)log((double)(-t1));
    float dlog = (l1 + g1) - (l0 + g0);
    float kp = 1.f / (1.f + expf(-dlog));
    policy[(size_t)b * 197 + 1 + n] = (dlog > 0.f) ? 1.f : 0.f;
    if (n == 0) policy[(size_t)b * 197] = 1.f;
    keep_prob[m] = kp;
}

__global__ __launch_bounds__(256)
void batch_reduce(const float* __restrict__ keep_prob, float* __restrict__ sum_kp)
{
    __shared__ float part[4];
    int b = blockIdx.x, tid = threadIdx.x;
    float vs = (tid < Nv_) ? keep_prob[(size_t)b * Nv_ + tid] : 0.f;
#pragma unroll
    for (int off = 32; off; off >>= 1) vs += __shfl_xor(vs, off, 64);
    if ((tid & 63) == 0) part[tid >> 6] = vs;
    __syncthreads();
    if (tid == 0) sum_kp[b] = part[0] + part[1] + part[2] + part[3];
}

__global__ __launch_bounds__(256)
void pw_scale(float* __restrict__ phi, const float* __restrict__ keep_prob,
              const float* __restrict__ sum_kp)
{
    int m = blockIdx.x * 4 + (threadIdx.x >> 6);
    int lane = threadIdx.x & 63;
    float4* row = (float4*)phi + (size_t)m * 64;
    float4 vv = row[lane];
    float ss = vv.x * vv.x + vv.y * vv.y + vv.z * vv.z + vv.w * vv.w;
#pragma unroll
    for (int off = 32; off; off >>= 1) ss += __shfl_xor(ss, off, 64);
    float nrm = fmaxf(sqrtf(ss), 1e-12f);
    int b = m / Nv_;
    float kp = keep_prob[m];
    float meanw = sum_kp[b] * (1.f / 196.f);
    float wn = fmaxf(kp / (meanw + 1e-12f), 1e-6f);
    float sc = sqrtf(wn) / nrm;
    vv.x *= sc; vv.y *= sc; vv.z *= sc; vv.w *= sc;
    row[lane] = vv;
}

// ---------------------------------------------------------------------------
// Per-batch blocked Cholesky logdet, panel-in-registers (r8-verified).
// ---------------------------------------------------------------------------
#define LS_   197
#define PBS_  14

__global__ __launch_bounds__(256)
void chol_kernel(const float* __restrict__ G, float* __restrict__ logdet_arr)
{
    extern __shared__ float sm[];
    float* Am  = sm;                          // 196 * 197
    float (*colraw)[PBS_] = (float(*)[PBS_])(sm + 196 * LS_);
    const int b = blockIdx.x, tid = threadIdx.x;
    const float* Gb = G + (size_t)b * Nv_ * Nv_;

    for (int idx = tid; idx < Nv_ * 49; idx += 256) {
        int i = idx / 49, c4 = (idx - i * 49) * 4;
        float4 v = *(const float4*)(Gb + (size_t)i * Nv_ + c4);
        if (i >= c4 && i < c4 + 4) (&v.x)[i - c4] += 1.00001f;
        float* dst = Am + i * LS_ + c4;
        dst[0] = v.x; dst[1] = v.y; dst[2] = v.z; dst[3] = v.w;
    }
    __syncthreads();

    float acc = 0.f;
    const int tx = tid & 15, ty = tid >> 4;

    for (int p = 0; p < Nv_ / PBS_; ++p) {
        const int j0 = p * PBS_;
        const int j1 = j0 + PBS_;
        const int i = tid;
        const bool haveRow = (i >= j0 && i < Nv_);

        float Rp[PBS_];
        if (haveRow) {
#pragma unroll
            for (int t = 0; t < PBS_; ++t) Rp[t] = Am[i * LS_ + j0 + t];
            if (i < j1) colraw[0][i - j0] = Rp[0];
        }

        for (int jj = 0; jj < PBS_; ++jj) {
            __syncthreads();
            const int j = j0 + jj;
            float piv = colraw[jj][jj];
            if (tid == 0) acc += logf(piv);
            float inv = 1.f / sqrtf(piv);
            if (haveRow && i >= j) {
                float lij = Rp[jj] * inv;
                Rp[jj] = lij;
#pragma unroll
                for (int k = 0; k < PBS_; ++k) {
                    if (k > jj) {
                        float lk = colraw[jj][k] * inv;
                        Rp[k] = fmaf(-lij, lk, Rp[k]);
                    }
                }
                if (jj < PBS_ - 1 && i > j && i < j1)
                    colraw[jj + 1][i - j0] = Rp[jj + 1];
            }
        }

        if (haveRow) {
#pragma unroll
            for (int t = 0; t < PBS_; ++t) Am[i * LS_ + j0 + t] = Rp[t];
        }
        __syncthreads();

        if (j1 >= Nv_) break;
        const int s = Nv_ - j1;
        const int nb = (s + 63) >> 6;
        for (int rb = 0; rb < nb; ++rb) {
            const int i0 = j1 + rb * 64;
            float Li[4][PBS_];
#pragma unroll
            for (int r = 0; r < 4; ++r) {
                int ir = i0 + ty + 16 * r; if (ir > 195) ir = 195;
#pragma unroll
                for (int t = 0; t < PBS_; ++t) Li[r][t] = Am[ir * LS_ + j0 + t];
            }
            for (int cb = 0; cb <= rb; ++cb) {
                const int k0 = j1 + cb * 64;
                float accs[4][4];
#pragma unroll
                for (int r = 0; r < 4; ++r)
#pragma unroll
                    for (int c = 0; c < 4; ++c) accs[r][c] = 0.f;
#pragma unroll
                for (int t = 0; t < PBS_; ++t) {
                    float Lk[4];
#pragma unroll
                    for (int c = 0; c < 4; ++c) {
                        int kx = k0 + 4 * tx + c; if (kx > 195) kx = 195;
                        Lk[c] = Am[kx * LS_ + j0 + t];
                    }
#pragma unroll
                    for (int r = 0; r < 4; ++r)
#pragma unroll
                        for (int c = 0; c < 4; ++c)
                            accs[r][c] = fmaf(Li[r][t], Lk[c], accs[r][c]);
                }
#pragma unroll
                for (int r = 0; r < 4; ++r) {
                    int ir = i0 + ty + 16 * r;
                    if (ir < Nv_) {
#pragma unroll
                        for (int c = 0; c < 4; ++c) {
                            int kx = k0 + 4 * tx + c;
                            if (kx < Nv_) Am[ir * LS_ + kx] -= accs[r][c];
                        }
                    }
                }
            }
        }
        __syncthreads();
    }
    if (tid == 0) logdet_arr[b] = acc;
}

__global__ void finalize_kernel(const float* __restrict__ sum_kp,
                                const float* __restrict__ logdet_arr,
                                float* __restrict__ out)
{
    float tot = 0.f, ld = 0.f;
    for (int b = 0; b < B_; ++b) { tot += sum_kp[b]; ld += logdet_arr[b]; }
    float mean = tot * (1.f / 25088.f);
    float d = mean - 0.7f;
    out[25216] = d * d;
    out[25217] = -ld * (1.f / 128.f);
}

// ---------------------------------------------------------------------------
extern "C" void kernel_launch(void* const* d_in, const int* in_sizes, int n_in,
                              void* d_out, int out_size, void* d_ws, size_t ws_size,
                              hipStream_t stream)
{
    const float* x      = (const float*)d_in[0];
    const float* text   = (const float*)d_in[1];
    const float* gumbel = (const float*)d_in[2];
    const float* Wq     = (const float*)d_in[3];
    const float* bq     = (const float*)d_in[4];
    const float* Wk     = (const float*)d_in[5];
    const float* bk     = (const float*)d_in[6];
    const float* Wv     = (const float*)d_in[7];
    const float* bv     = (const float*)d_in[8];
    const float* W1     = (const float*)d_in[9];
    const float* b1     = (const float*)d_in[10];
    const float* W2     = (const float*)d_in[11];
    const float* b2     = (const float*)d_in[12];
    const float* Wdpp   = (const float*)d_in[13];
    float* out = (float*)d_out;

    float* ws = (float*)d_ws;
    float* q          = ws;                       // 19,267,584 f ; reused as G
    float* kbuf       = q + 19267584;
    float* vbuf       = kbuf + 3145728;
    float* phi        = vbuf + 3145728;
    float* partials   = phi + 6422528;            // 25088*24
    float* keep_prob  = partials + 602112;
    float* sum_kp     = keep_prob + 25088;
    float* logdet_arr = sum_kp + 128;
    float* G          = ws;

    short* Wq_h = (short*)(logdet_arr + 128);
    short* Wq_l = Wq_h + 589824;
    short* W1_h = Wq_l + 589824;
    short* W1_l = W1_h + 589824;
    short* Wk_h = W1_l + 589824;
    short* Wk_l = Wk_h + 393216;
    short* Wv_h = Wk_l + 393216;
    short* Wv_l = Wv_h + 393216;
    short* Wd_h = Wv_l + 393216;
    short* Wd_l = Wd_h + 196608;

    dim3 blk(256);

    // fused weight pre-split (one launch)
    split_all<<<dim3(8448), blk, 0, stream>>>(Wq, W1, Wk, Wv, Wdpp,
                                              Wq_h, Wq_l, W1_h, W1_l,
                                              Wk_h, Wk_l, Wv_h, Wv_l,
                                              Wd_h, Wd_l);

    // k+v projections merged (z=0 -> k, z=1 -> v): M=4096, N=768, K=512
    mfma_gemm<0,0><<<dim3(32,6,2), blk, 0, stream>>>(text, Wk_h, Wk_l, bk, kbuf, 768, 512,
                                                     nullptr, nullptr,
                                                     Wv_h, Wv_l, bv, vbuf);
    // q projection (gathered vis_tok): M=25088, N=768, K=768
    mfma_gemm<1,0><<<dim3(196,6,1), blk, 0, stream>>>(x, Wq_h, Wq_l, bq, q, 768, 768,
                                                      nullptr, nullptr,
                                                      Wq_h, Wq_l, bq, q);
    attn_kernel<<<dim3(B_*H_), blk, 0, stream>>>(q, kbuf, vbuf, x, q);
    // MLP with gelu/W2 epilogue
    mfma_gemm<0,1><<<dim3(196,6,1), blk, 0, stream>>>(q, W1_h, W1_l, b1, nullptr, 768, 768,
                                                      W2, partials,
                                                      W1_h, W1_l, b1, nullptr);
    keep_kernel<<<dim3(98), blk, 0, stream>>>(partials, b2, gumbel, out, keep_prob);
    batch_reduce<<<dim3(B_), blk, 0, stream>>>(keep_prob, sum_kp);
    // phi projection: M=25088, N=256, K=768
    mfma_gemm<1,0><<<dim3(196,2,1), blk, 0, stream>>>(x, Wd_h, Wd_l, nullptr, phi, 256, 768,
                                                      nullptr, nullptr,
                                                      Wd_h, Wd_l, nullptr, phi);
    pw_scale<<<dim3(6272), blk, 0, stream>>>(phi, keep_prob, sum_kp);
    gemm_nt<0,1,0><<<dim3(2,2,B_), blk, 0, stream>>>(phi, phi, nullptr, G, Nv_, Nv_, 256,
                                                     1.0f/(256.0f*196.0f*0.01f),
                                                     (long)Nv_*256, (long)Nv_*Nv_, nullptr, nullptr);
    size_t shb = (size_t)(Nv_ * LS_ + Nv_) * sizeof(float);
    (void)hipFuncSetAttribute((const void*)chol_kernel,
                              hipFuncAttributeMaxDynamicSharedMemorySize, (int)shb);
    chol_kernel<<<dim3(B_), blk, shb, stream>>>(G, logdet_arr);
    finalize_kernel<<<dim3(1), dim3(1), 0, stream>>>(sum_kp, logdet_arr, out);
}

// Round 10
// 649.782 us; speedup vs baseline: 3.1709x; 1.1066x over previous
//
#include <hip/hip_runtime.h>
#include <math.h>

#define B_   128
#define L_   197
#define C_   768
#define Nv_  196
#define Lt_  32
#define Ct_  512
#define H_   12
#define DH_  64
#define DPP_ 256
#define MTOK 25088   // B_*Nv_

typedef __attribute__((ext_vector_type(8))) short bf16x8_t;
typedef __attribute__((ext_vector_type(4))) float f32x4_t;

// split fp32 -> bf16 hi (truncate) + bf16 lo (RNE of remainder)
__device__ __forceinline__ void split_bf16(float a, unsigned &h, unsigned &l) {
    unsigned u = __float_as_uint(a);
    unsigned hu = u & 0xffff0000u;
    h = hu >> 16;
    float lf = a - __uint_as_float(hu);
    unsigned ul = __float_as_uint(lf);
    l = (ul + 0x7fffu + ((ul >> 16) & 1u)) >> 16;
}

// ---------------------------------------------------------------------------
// fused weight pre-split (all 5 weights in one launch)
// ---------------------------------------------------------------------------
#define NWQ 589824
#define NWK 393216
#define NWD 196608
__global__ __launch_bounds__(256)
void split_all(const float* __restrict__ Wq, const float* __restrict__ W1,
               const float* __restrict__ Wk, const float* __restrict__ Wv,
               const float* __restrict__ Wd,
               short* __restrict__ Wq_h, short* __restrict__ Wq_l,
               short* __restrict__ W1_h, short* __restrict__ W1_l,
               short* __restrict__ Wk_h, short* __restrict__ Wk_l,
               short* __restrict__ Wv_h, short* __restrict__ Wv_l,
               short* __restrict__ Wd_h, short* __restrict__ Wd_l)
{
    int j = blockIdx.x * 256 + threadIdx.x;   // total 2,162,688 = 8448*256
    const float* src; short *hi, *lo;
    if (j < NWQ)                { src = Wq; hi = Wq_h; lo = Wq_l; }
    else if ((j -= NWQ) < NWQ)  { src = W1; hi = W1_h; lo = W1_l; }
    else if ((j -= NWQ) < NWK)  { src = Wk; hi = Wk_h; lo = Wk_l; }
    else if ((j -= NWK) < NWK)  { src = Wv; hi = Wv_h; lo = Wv_l; }
    else                        { j -= NWK;  src = Wd; hi = Wd_h; lo = Wd_l; }
    unsigned h, l;
    split_bf16(src[j], h, l);
    hi[j] = (short)h; lo[j] = (short)l;
}

// ---------------------------------------------------------------------------
// 3-term split-bf16 MFMA GEMM (r6-verified): C = A*W^T (+bias)
// acc += Ah*Bh + Ah*Bl + Al*Bh  (fp32 MFMA accumulate, err ~2^-17)
// blockIdx.z==1 selects the second (B,bias,C) set (merged k/v launch).
// ---------------------------------------------------------------------------
template<int GATHER, int EPI>
__global__ __launch_bounds__(256)
void mfma_gemm(const float* __restrict__ A, const short* __restrict__ Bh_g,
               const short* __restrict__ Bl_g, const float* __restrict__ bias,
               float* __restrict__ Cst, int Nst, int Kd,
               const float* __restrict__ W2, float* __restrict__ partials,
               const short* Bh2, const short* Bl2, const float* bias2,
               float* Cst2)
{
    if (blockIdx.z) { Bh_g = Bh2; Bl_g = Bl2; bias = bias2; Cst = Cst2; }
    __shared__ short Ah[128 * 40], Al[128 * 40], Bh[128 * 40], Bl[128 * 40];
    const int tid = threadIdx.x;
    const int m0 = blockIdx.x * 128, n0 = blockIdx.y * 128;
    const int l = tid & 63, wid = tid >> 6;
    const int wr = wid >> 1, wc = wid & 1;
    const int lr = l & 15, lq = l >> 4;

    const int srow = tid >> 2;
    const int p8 = (tid & 3) << 3;
    const float* aptr[2]; const short* bhp[2]; const short* blp[2];
    int abase[2];
#pragma unroll
    for (int i = 0; i < 2; ++i) {
        int row = srow + i * 64;
        abase[i] = row * 40 + p8;
        int gr = m0 + row;
        if (GATHER) {
            int bb = gr / Nv_, n = gr - bb * Nv_;
            aptr[i] = A + ((size_t)(n + 1) * B_ + bb) * C_ + p8;
        } else {
            aptr[i] = A + (size_t)gr * Kd + p8;
        }
        int gc = n0 + row;
        bhp[i] = Bh_g + (size_t)gc * Kd + p8;
        blp[i] = Bl_g + (size_t)gc * Kd + p8;
    }

    f32x4_t acc[4][4];
#pragma unroll
    for (int m = 0; m < 4; ++m)
#pragma unroll
        for (int n = 0; n < 4; ++n) {
            acc[m][n][0] = 0.f; acc[m][n][1] = 0.f;
            acc[m][n][2] = 0.f; acc[m][n][3] = 0.f;
        }

    for (int k0 = 0; k0 < Kd; k0 += 32) {
#pragma unroll
        for (int i = 0; i < 2; ++i) {
            const float* s = aptr[i] + k0;
            float4 f0 = *(const float4*)s;
            float4 f1 = *(const float4*)(s + 4);
            float av[8] = {f0.x, f0.y, f0.z, f0.w, f1.x, f1.y, f1.z, f1.w};
            unsigned hv[8], lv[8];
#pragma unroll
            for (int j = 0; j < 8; ++j) split_bf16(av[j], hv[j], lv[j]);
            uint4 Hh, Ll;
            Hh.x = hv[0] | (hv[1] << 16); Hh.y = hv[2] | (hv[3] << 16);
            Hh.z = hv[4] | (hv[5] << 16); Hh.w = hv[6] | (hv[7] << 16);
            Ll.x = lv[0] | (lv[1] << 16); Ll.y = lv[2] | (lv[3] << 16);
            Ll.z = lv[4] | (lv[5] << 16); Ll.w = lv[6] | (lv[7] << 16);
            *(uint4*)&Ah[abase[i]] = Hh;
            *(uint4*)&Al[abase[i]] = Ll;
            *(uint4*)&Bh[abase[i]] = *(const uint4*)(bhp[i] + k0);
            *(uint4*)&Bl[abase[i]] = *(const uint4*)(blp[i] + k0);
        }
        __syncthreads();

        bf16x8_t ahf[4], alf[4], bhf[4], blf[4];
#pragma unroll
        for (int m = 0; m < 4; ++m) {
            int ro = (wr * 64 + m * 16 + lr) * 40 + lq * 8;
            ahf[m] = *(const bf16x8_t*)&Ah[ro];
            alf[m] = *(const bf16x8_t*)&Al[ro];
        }
#pragma unroll
        for (int n = 0; n < 4; ++n) {
            int ro = (wc * 64 + n * 16 + lr) * 40 + lq * 8;
            bhf[n] = *(const bf16x8_t*)&Bh[ro];
            blf[n] = *(const bf16x8_t*)&Bl[ro];
        }
#pragma unroll
        for (int m = 0; m < 4; ++m)
#pragma unroll
            for (int n = 0; n < 4; ++n) {
                acc[m][n] = __builtin_amdgcn_mfma_f32_16x16x32_bf16(ahf[m], bhf[n], acc[m][n], 0, 0, 0);
                acc[m][n] = __builtin_amdgcn_mfma_f32_16x16x32_bf16(ahf[m], blf[n], acc[m][n], 0, 0, 0);
                acc[m][n] = __builtin_amdgcn_mfma_f32_16x16x32_bf16(alf[m], bhf[n], acc[m][n], 0, 0, 0);
            }
        __syncthreads();
    }

    if constexpr (EPI == 0) {
#pragma unroll
        for (int n = 0; n < 4; ++n) {
            int col = n0 + wc * 64 + n * 16 + lr;
            float bv = bias ? bias[col] : 0.f;
#pragma unroll
            for (int m = 0; m < 4; ++m) {
                int rowb = m0 + wr * 64 + m * 16 + lq * 4;
#pragma unroll
                for (int r = 0; r < 4; ++r)
                    Cst[(size_t)(rowb + r) * Nst + col] = acc[m][n][r] + bv;
            }
        }
    } else {
        int coln[4]; float b1v[4], w20[4], w21[4];
#pragma unroll
        for (int n = 0; n < 4; ++n) {
            coln[n] = n0 + wc * 64 + n * 16 + lr;
            b1v[n] = bias[coln[n]];
            w20[n] = W2[coln[n]];
            w21[n] = W2[C_ + coln[n]];
        }
        const int pi = (blockIdx.y * 2 + wc) * 2;
#pragma unroll
        for (int m = 0; m < 4; ++m)
#pragma unroll
            for (int r = 0; r < 4; ++r) {
                float p0 = 0.f, p1 = 0.f;
#pragma unroll
                for (int n = 0; n < 4; ++n) {
                    float h = acc[m][n][r] + b1v[n];
                    float gl = h / (1.f + expf(-1.702f * h));
                    p0 = fmaf(gl, w20[n], p0);
                    p1 = fmaf(gl, w21[n], p1);
                }
#pragma unroll
                for (int off = 8; off; off >>= 1) {
                    p0 += __shfl_xor(p0, off, 16);
                    p1 += __shfl_xor(p1, off, 16);
                }
                if (lr == 0) {
                    int row = m0 + wr * 64 + m * 16 + lq * 4 + r;
                    partials[(size_t)row * 24 + pi + 0] = p0;
                    partials[(size_t)row * 24 + pi + 1] = p1;
                }
            }
    }
}

// ---------------------------------------------------------------------------
// fp32 NT GEMM (batched gram only). r5-verified.
// ---------------------------------------------------------------------------
template<int GATHER_A, int BOUNDS, int EPI>
__global__ __launch_bounds__(256)
void gemm_nt(const float* __restrict__ A, const float* __restrict__ Bm,
             const float* __restrict__ bias, float* __restrict__ C,
             int M, int N, int K, float scale,
             long strideA, long strideC,
             const float* __restrict__ W2, float* __restrict__ partials)
{
    __shared__ float As[16][132];
    __shared__ float Bs[16][132];
    const int tid = threadIdx.x;
    const int tx = tid & 15, ty = tid >> 4;
    const int m0 = blockIdx.x * 128, n0 = blockIdx.y * 128;
    const int bz = blockIdx.z;
    const float* Ab = A  + (size_t)bz * strideA;
    const float* Bb = Bm + (size_t)bz * strideA;
    float* Cb = C + (size_t)bz * strideC;

    const int lrow = tid >> 2;
    const int lk   = (tid & 3) << 2;

    const float* aptr[2]; const float* bptr[2];
    bool aval[2], bval[2];
#pragma unroll
    for (int Lq = 0; Lq < 2; ++Lq) {
        int row = lrow + Lq * 64;
        int gr = m0 + row;
        aval[Lq] = (!BOUNDS) || (gr < M);
        aptr[Lq] = Ab + (size_t)(aval[Lq] ? gr : 0) * K + lk;
        int gc = n0 + row;
        bval[Lq] = (!BOUNDS) || (gc < N);
        bptr[Lq] = Bb + (size_t)(bval[Lq] ? gc : 0) * K + lk;
    }

    float acc[8][8];
#pragma unroll
    for (int r = 0; r < 8; ++r)
#pragma unroll
        for (int c = 0; c < 8; ++c) acc[r][c] = 0.f;

    for (int k0 = 0; k0 < K; k0 += 16) {
#pragma unroll
        for (int Lq = 0; Lq < 2; ++Lq) {
            int row = lrow + Lq * 64;
            float4 va = aval[Lq] ? *(const float4*)(aptr[Lq] + k0)
                                 : make_float4(0.f, 0.f, 0.f, 0.f);
            As[lk+0][row] = va.x; As[lk+1][row] = va.y;
            As[lk+2][row] = va.z; As[lk+3][row] = va.w;
            float4 vb = bval[Lq] ? *(const float4*)(bptr[Lq] + k0)
                                 : make_float4(0.f, 0.f, 0.f, 0.f);
            Bs[lk+0][row] = vb.x; Bs[lk+1][row] = vb.y;
            Bs[lk+2][row] = vb.z; Bs[lk+3][row] = vb.w;
        }
        __syncthreads();
#pragma unroll
        for (int kk = 0; kk < 16; ++kk) {
            float a[8], bfr[8];
            *(float4*)&a[0]   = *(const float4*)&As[kk][ty * 8];
            *(float4*)&a[4]   = *(const float4*)&As[kk][ty * 8 + 4];
            *(float4*)&bfr[0] = *(const float4*)&Bs[kk][tx * 4];
            *(float4*)&bfr[4] = *(const float4*)&Bs[kk][64 + tx * 4];
#pragma unroll
            for (int r = 0; r < 8; ++r)
#pragma unroll
                for (int c = 0; c < 8; ++c)
                    acc[r][c] = fmaf(a[r], bfr[c], acc[r][c]);
        }
        __syncthreads();
    }

#pragma unroll
    for (int r = 0; r < 8; ++r) {
        int gr = m0 + ty * 8 + r;
        if (BOUNDS && gr >= M) continue;
#pragma unroll
        for (int half = 0; half < 2; ++half) {
            int gc = n0 + half * 64 + tx * 4;
#pragma unroll
            for (int c = 0; c < 4; ++c) {
                if (!BOUNDS || gc + c < N) {
                    float v = acc[r][half*4+c] * scale;
                    if (bias) v += bias[gc+c];
                    Cb[(size_t)gr * N + gc + c] = v;
                }
            }
        }
    }
}

// ---------------------------------------------------------------------------
// Attention per (b,h): 4 rows per wave per iteration. Score phase uses ALL
// 64 lanes: lanes 0-31 compute rows base+0,+1; lanes 32-63 rows base+2,+3
// (key = lane&31; width-32 shuffle butterflies stay within halves, so
// per-row softmax semantics are identical). PV accumulates 4 rows on all
// lanes. base = it*16 + wv*4 <= 192 always full (196 = 12*16+4) -> no row
// guards. Per-row FMA order identical to r9 -> bit-identical output.
// q/x prefetch one iteration ahead; wave-private qs/as; no in-loop barriers.
// ---------------------------------------------------------------------------
__global__ __launch_bounds__(256)
void attn_kernel(const float* __restrict__ q, const float* __restrict__ k,
                 const float* __restrict__ v, const float* __restrict__ x,
                 float* __restrict__ fused)
{
    __shared__ float Ks[Lt_][DH_ + 4];
    __shared__ float Vs[Lt_][DH_ + 1];
    __shared__ float qs[16][DH_];
    __shared__ float as[16][Lt_];
    const int bh = blockIdx.x;
    const int b = bh / H_, h = bh - b * H_;
    const int tid = threadIdx.x;
    const int wv = tid >> 6, lane = tid & 63;
    const int half = lane >> 5;         // 0: rows +0,+1 ; 1: rows +2,+3
    const int key = lane & 31;

    for (int idx = tid; idx < Lt_ * 16; idx += 256) {
        int l = idx >> 4, dq = (idx & 15) << 2;
        size_t off = ((size_t)(b * Lt_ + l)) * C_ + h * DH_ + dq;
        float4 kv4 = *(const float4*)(k + off);
        Ks[l][dq] = kv4.x; Ks[l][dq + 1] = kv4.y; Ks[l][dq + 2] = kv4.z; Ks[l][dq + 3] = kv4.w;
        float4 vv4 = *(const float4*)(v + off);
        Vs[l][dq] = vv4.x; Vs[l][dq + 1] = vv4.y; Vs[l][dq + 2] = vv4.z; Vs[l][dq + 3] = vv4.w;
    }
    __syncthreads();

    const size_t qbase = (size_t)b * Nv_ * C_ + h * DH_ + lane;
    const size_t xbase = (size_t)b * C_ + h * DH_ + lane;
    // q row n -> q[qbase + n*C_]; x row n -> x[xbase + (n+1)*B_*C_]

    // prologue: rows for it=0 (base = wv*4)
    float qv[4], xv[4];
#pragma unroll
    for (int j = 0; j < 4; ++j) {
        qv[j] = q[qbase + (size_t)(wv * 4 + j) * C_];
        xv[j] = x[xbase + (size_t)(wv * 4 + j + 1) * B_ * C_];
    }

    for (int it = 0; it < 13; ++it) {
        const int base = it * 16 + wv * 4;
        if (base > 192) break;              // only wv>0 at it==12
        float cq[4], cx[4];
#pragma unroll
        for (int j = 0; j < 4; ++j) { cq[j] = qv[j]; cx[j] = xv[j]; }
        const int nbase = base + 16;
        if (nbase <= 192) {                 // prefetch next iteration
#pragma unroll
            for (int j = 0; j < 4; ++j) {
                qv[j] = q[qbase + (size_t)(nbase + j) * C_];
                xv[j] = x[xbase + (size_t)(nbase + j + 1) * B_ * C_];
            }
        }
        const int ws = wv * 4;              // wave's qs/as slot base
#pragma unroll
        for (int j = 0; j < 4; ++j) qs[ws + j][lane] = cq[j];

        // score: 2 rows per lane-half (slots ws+half*2, +1), key = lane&31
        const int s0 = ws + half * 2;
        float s1 = 0.f, s2 = 0.f;
#pragma unroll
        for (int d4 = 0; d4 < DH_; d4 += 4) {
            float4 k4  = *(const float4*)&Ks[key][d4];
            float4 q4a = *(const float4*)&qs[s0][d4];
            float4 q4b = *(const float4*)&qs[s0 + 1][d4];
            s1 = fmaf(q4a.x, k4.x, s1); s2 = fmaf(q4b.x, k4.x, s2);
            s1 = fmaf(q4a.y, k4.y, s1); s2 = fmaf(q4b.y, k4.y, s2);
            s1 = fmaf(q4a.z, k4.z, s1); s2 = fmaf(q4b.z, k4.z, s2);
            s1 = fmaf(q4a.w, k4.w, s1); s2 = fmaf(q4b.w, k4.w, s2);
        }
        s1 *= 0.125f; s2 *= 0.125f;
        float mx1 = s1, mx2 = s2;
#pragma unroll
        for (int off = 16; off; off >>= 1) {
            mx1 = fmaxf(mx1, __shfl_xor(mx1, off, 32));
            mx2 = fmaxf(mx2, __shfl_xor(mx2, off, 32));
        }
        float p1v = expf(s1 - mx1);
        float p2v = expf(s2 - mx2);
        float su1 = p1v, su2 = p2v;
#pragma unroll
        for (int off = 16; off; off >>= 1) {
            su1 += __shfl_xor(su1, off, 32);
            su2 += __shfl_xor(su2, off, 32);
        }
        as[s0][key] = p1v / su1;
        as[s0 + 1][key] = p2v / su2;

        // PV: 4 rows on all 64 lanes (dim = lane)
        float c0 = 0.f, c1 = 0.f, c2 = 0.f, c3 = 0.f;
#pragma unroll
        for (int l4 = 0; l4 < Lt_; l4 += 4) {
            float4 a0 = *(const float4*)&as[ws + 0][l4];
            float4 a1 = *(const float4*)&as[ws + 1][l4];
            float4 a2 = *(const float4*)&as[ws + 2][l4];
            float4 a3 = *(const float4*)&as[ws + 3][l4];
            float v0 = Vs[l4 + 0][lane], v1 = Vs[l4 + 1][lane];
            float v2 = Vs[l4 + 2][lane], v3 = Vs[l4 + 3][lane];
            c0 = fmaf(a0.x, v0, c0); c1 = fmaf(a1.x, v0, c1);
            c2 = fmaf(a2.x, v0, c2); c3 = fmaf(a3.x, v0, c3);
            c0 = fmaf(a0.y, v1, c0); c1 = fmaf(a1.y, v1, c1);
            c2 = fmaf(a2.y, v1, c2); c3 = fmaf(a3.y, v1, c3);
            c0 = fmaf(a0.z, v2, c0); c1 = fmaf(a1.z, v2, c1);
            c2 = fmaf(a2.z, v2, c2); c3 = fmaf(a3.z, v2, c3);
            c0 = fmaf(a0.w, v3, c0); c1 = fmaf(a1.w, v3, c1);
            c2 = fmaf(a2.w, v3, c2); c3 = fmaf(a3.w, v3, c3);
        }
        fused[qbase + (size_t)(base + 0) * C_] = c0 + cx[0];
        fused[qbase + (size_t)(base + 1) * C_] = c1 + cx[1];
        fused[qbase + (size_t)(base + 2) * C_] = c2 + cx[2];
        fused[qbase + (size_t)(base + 3) * C_] = c3 + cx[3];
    }
}

// ---------------------------------------------------------------------------
// keep decisions: logits from partials[m][24] (+b2), gumbel, policy, keep_prob
// ---------------------------------------------------------------------------
__global__ __launch_bounds__(256)
void keep_kernel(const float* __restrict__ partials, const float* __restrict__ b2,
                 const float* __restrict__ gumbel, float* __restrict__ policy,
                 float* __restrict__ keep_prob)
{
    int m = blockIdx.x * 256 + threadIdx.x;
    int b = m / Nv_, n = m - b * Nv_;
    float l0 = b2[0], l1 = b2[1];
#pragma unroll
    for (int t = 0; t < 12; ++t) {
        l0 += partials[(size_t)m * 24 + t * 2 + 0];
        l1 += partials[(size_t)m * 24 + t * 2 + 1];
    }
    const float UHI = (float)(1.0 - 1e-6);
    float U0 = fminf(fmaxf(gumbel[(size_t)m * 2 + 0], 1e-6f), UHI);
    float U1 = fminf(fmaxf(gumbel[(size_t)m * 2 + 1], 1e-6f), UHI);
    float t0 = (float)log((double)U0);
    float g0 = -(float)log((double)(-t0));
    float t1 = (float)log((double)U1);
    float g1 = -(float)log((double)(-t1));
    float dlog = (l1 + g1) - (l0 + g0);
    float kp = 1.f / (1.f + expf(-dlog));
    policy[(size_t)b * 197 + 1 + n] = (dlog > 0.f) ? 1.f : 0.f;
    if (n == 0) policy[(size_t)b * 197] = 1.f;
    keep_prob[m] = kp;
}

__global__ __launch_bounds__(256)
void batch_reduce(const float* __restrict__ keep_prob, float* __restrict__ sum_kp)
{
    __shared__ float part[4];
    int b = blockIdx.x, tid = threadIdx.x;
    float vs = (tid < Nv_) ? keep_prob[(size_t)b * Nv_ + tid] : 0.f;
#pragma unroll
    for (int off = 32; off; off >>= 1) vs += __shfl_xor(vs, off, 64);
    if ((tid & 63) == 0) part[tid >> 6] = vs;
    __syncthreads();
    if (tid == 0) sum_kp[b] = part[0] + part[1] + part[2] + part[3];
}

__global__ __launch_bounds__(256)
void pw_scale(float* __restrict__ phi, const float* __restrict__ keep_prob,
              const float* __restrict__ sum_kp)
{
    int m = blockIdx.x * 4 + (threadIdx.x >> 6);
    int lane = threadIdx.x & 63;
    float4* row = (float4*)phi + (size_t)m * 64;
    float4 vv = row[lane];
    float ss = vv.x * vv.x + vv.y * vv.y + vv.z * vv.z + vv.w * vv.w;
#pragma unroll
    for (int off = 32; off; off >>= 1) ss += __shfl_xor(ss, off, 64);
    float nrm = fmaxf(sqrtf(ss), 1e-12f);
    int b = m / Nv_;
    float kp = keep_prob[m];
    float meanw = sum_kp[b] * (1.f / 196.f);
    float wn = fmaxf(kp / (meanw + 1e-12f), 1e-6f);
    float sc = sqrtf(wn) / nrm;
    vv.x *= sc; vv.y *= sc; vv.z *= sc; vv.w *= sc;
    row[lane] = vv;
}

// ---------------------------------------------------------------------------
// Per-batch blocked Cholesky logdet, panel-in-registers (r8-verified).
// ---------------------------------------------------------------------------
#define LS_   197
#define PBS_  14

__global__ __launch_bounds__(256)
void chol_kernel(const float* __restrict__ G, float* __restrict__ logdet_arr)
{
    extern __shared__ float sm[];
    float* Am  = sm;                          // 196 * 197
    float (*colraw)[PBS_] = (float(*)[PBS_])(sm + 196 * LS_);
    const int b = blockIdx.x, tid = threadIdx.x;
    const float* Gb = G + (size_t)b * Nv_ * Nv_;

    for (int idx = tid; idx < Nv_ * 49; idx += 256) {
        int i = idx / 49, c4 = (idx - i * 49) * 4;
        float4 v = *(const float4*)(Gb + (size_t)i * Nv_ + c4);
        if (i >= c4 && i < c4 + 4) (&v.x)[i - c4] += 1.00001f;
        float* dst = Am + i * LS_ + c4;
        dst[0] = v.x; dst[1] = v.y; dst[2] = v.z; dst[3] = v.w;
    }
    __syncthreads();

    float acc = 0.f;
    const int tx = tid & 15, ty = tid >> 4;

    for (int p = 0; p < Nv_ / PBS_; ++p) {
        const int j0 = p * PBS_;
        const int j1 = j0 + PBS_;
        const int i = tid;
        const bool haveRow = (i >= j0 && i < Nv_);

        float Rp[PBS_];
        if (haveRow) {
#pragma unroll
            for (int t = 0; t < PBS_; ++t) Rp[t] = Am[i * LS_ + j0 + t];
            if (i < j1) colraw[0][i - j0] = Rp[0];
        }

        for (int jj = 0; jj < PBS_; ++jj) {
            __syncthreads();
            const int j = j0 + jj;
            float piv = colraw[jj][jj];
            if (tid == 0) acc += logf(piv);
            float inv = 1.f / sqrtf(piv);
            if (haveRow && i >= j) {
                float lij = Rp[jj] * inv;
                Rp[jj] = lij;
#pragma unroll
                for (int k = 0; k < PBS_; ++k) {
                    if (k > jj) {
                        float lk = colraw[jj][k] * inv;
                        Rp[k] = fmaf(-lij, lk, Rp[k]);
                    }
                }
                if (jj < PBS_ - 1 && i > j && i < j1)
                    colraw[jj + 1][i - j0] = Rp[jj + 1];
            }
        }

        if (haveRow) {
#pragma unroll
            for (int t = 0; t < PBS_; ++t) Am[i * LS_ + j0 + t] = Rp[t];
        }
        __syncthreads();

        if (j1 >= Nv_) break;
        const int s = Nv_ - j1;
        const int nb = (s + 63) >> 6;
        for (int rb = 0; rb < nb; ++rb) {
            const int i0 = j1 + rb * 64;
            float Li[4][PBS_];
#pragma unroll
            for (int r = 0; r < 4; ++r) {
                int ir = i0 + ty + 16 * r; if (ir > 195) ir = 195;
#pragma unroll
                for (int t = 0; t < PBS_; ++t) Li[r][t] = Am[ir * LS_ + j0 + t];
            }
            for (int cb = 0; cb <= rb; ++cb) {
                const int k0 = j1 + cb * 64;
                float accs[4][4];
#pragma unroll
                for (int r = 0; r < 4; ++r)
#pragma unroll
                    for (int c = 0; c < 4; ++c) accs[r][c] = 0.f;
#pragma unroll
                for (int t = 0; t < PBS_; ++t) {
                    float Lk[4];
#pragma unroll
                    for (int c = 0; c < 4; ++c) {
                        int kx = k0 + 4 * tx + c; if (kx > 195) kx = 195;
                        Lk[c] = Am[kx * LS_ + j0 + t];
                    }
#pragma unroll
                    for (int r = 0; r < 4; ++r)
#pragma unroll
                        for (int c = 0; c < 4; ++c)
                            accs[r][c] = fmaf(Li[r][t], Lk[c], accs[r][c]);
                }
#pragma unroll
                for (int r = 0; r < 4; ++r) {
                    int ir = i0 + ty + 16 * r;
                    if (ir < Nv_) {
#pragma unroll
                        for (int c = 0; c < 4; ++c) {
                            int kx = k0 + 4 * tx + c;
                            if (kx < Nv_) Am[ir * LS_ + kx] -= accs[r][c];
                        }
                    }
                }
            }
        }
        __syncthreads();
    }
    if (tid == 0) logdet_arr[b] = acc;
}

__global__ void finalize_kernel(const float* __restrict__ sum_kp,
                                const float* __restrict__ logdet_arr,
                                float* __restrict__ out)
{
    float tot = 0.f, ld = 0.f;
    for (int b = 0; b < B_; ++b) { tot += sum_kp[b]; ld += logdet_arr[b]; }
    float mean = tot * (1.f / 25088.f);
    float d = mean - 0.7f;
    out[25216] = d * d;
    out[25217] = -ld * (1.f / 128.f);
}

// ---------------------------------------------------------------------------
extern "C" void kernel_launch(void* const* d_in, const int* in_sizes, int n_in,
                              void* d_out, int out_size, void* d_ws, size_t ws_size,
                              hipStream_t stream)
{
    const float* x      = (const float*)d_in[0];
    const float* text   = (const float*)d_in[1];
    const float* gumbel = (const float*)d_in[2];
    const float* Wq     = (const float*)d_in[3];
    const float* bq     = (const float*)d_in[4];
    const float* Wk     = (const float*)d_in[5];
    const float* bk     = (const float*)d_in[6];
    const float* Wv     = (const float*)d_in[7];
    const float* bv     = (const float*)d_in[8];
    const float* W1     = (const float*)d_in[9];
    const float* b1     = (const float*)d_in[10];
    const float* W2     = (const float*)d_in[11];
    const float* b2     = (const float*)d_in[12];
    const float* Wdpp   = (const float*)d_in[13];
    float* out = (float*)d_out;

    float* ws = (float*)d_ws;
    float* q          = ws;                       // 19,267,584 f ; reused as G
    float* kbuf       = q + 19267584;
    float* vbuf       = kbuf + 3145728;
    float* phi        = vbuf + 3145728;
    float* partials   = phi + 6422528;            // 25088*24
    float* keep_prob  = partials + 602112;
    float* sum_kp     = keep_prob + 25088;
    float* logdet_arr = sum_kp + 128;
    float* G          = ws;

    short* Wq_h = (short*)(logdet_arr + 128);
    short* Wq_l = Wq_h + 589824;
    short* W1_h = Wq_l + 589824;
    short* W1_l = W1_h + 589824;
    short* Wk_h = W1_l + 589824;
    short* Wk_l = Wk_h + 393216;
    short* Wv_h = Wk_l + 393216;
    short* Wv_l = Wv_h + 393216;
    short* Wd_h = Wv_l + 393216;
    short* Wd_l = Wd_h + 196608;

    dim3 blk(256);

    split_all<<<dim3(8448), blk, 0, stream>>>(Wq, W1, Wk, Wv, Wdpp,
                                              Wq_h, Wq_l, W1_h, W1_l,
                                              Wk_h, Wk_l, Wv_h, Wv_l,
                                              Wd_h, Wd_l);

    mfma_gemm<0,0><<<dim3(32,6,2), blk, 0, stream>>>(text, Wk_h, Wk_l, bk, kbuf, 768, 512,
                                                     nullptr, nullptr,
                                                     Wv_h, Wv_l, bv, vbuf);
    mfma_gemm<1,0><<<dim3(196,6,1), blk, 0, stream>>>(x, Wq_h, Wq_l, bq, q, 768, 768,
                                                      nullptr, nullptr,
                                                      Wq_h, Wq_l, bq, q);
    attn_kernel<<<dim3(B_*H_), blk, 0, stream>>>(q, kbuf, vbuf, x, q);
    mfma_gemm<0,1><<<dim3(196,6,1), blk, 0, stream>>>(q, W1_h, W1_l, b1, nullptr, 768, 768,
                                                      W2, partials,
                                                      W1_h, W1_l, b1, nullptr);
    keep_kernel<<<dim3(98), blk, 0, stream>>>(partials, b2, gumbel, out, keep_prob);
    batch_reduce<<<dim3(B_), blk, 0, stream>>>(keep_prob, sum_kp);
    mfma_gemm<1,0><<<dim3(196,2,1), blk, 0, stream>>>(x, Wd_h, Wd_l, nullptr, phi, 256, 768,
                                                      nullptr, nullptr,
                                                      Wd_h, Wd_l, nullptr, phi);
    pw_scale<<<dim3(6272), blk, 0, stream>>>(phi, keep_prob, sum_kp);
    gemm_nt<0,1,0><<<dim3(2,2,B_), blk, 0, stream>>>(phi, phi, nullptr, G, Nv_, Nv_, 256,
                                                     1.0f/(256.0f*196.0f*0.01f),
                                                     (long)Nv_*256, (long)Nv_*Nv_, nullptr, nullptr);
    size_t shb = (size_t)(Nv_ * LS_ + Nv_) * sizeof(float);
    (void)hipFuncSetAttribute((const void*)chol_kernel,
                              hipFuncAttributeMaxDynamicSharedMemorySize, (int)shb);
    chol_kernel<<<dim3(B_), blk, shb, stream>>>(G, logdet_arr);
    finalize_kernel<<<dim3(1), dim3(1), 0, stream>>>(sum_kp, logdet_arr, out);
}